// Round 1
// baseline (315.632 us; speedup 1.0000x reference)
//
#include <hip/hip_runtime.h>
#include <stdint.h>

#define HH 1024
#define WW 1024
#define NB 16
#define KTOP 512
#define TILE 64
#define NBINS 4096
#define CAP 8192

typedef unsigned long long u64;
typedef unsigned int u32;

__device__ __forceinline__ u32 fmap(float v) {
    u32 u = __float_as_uint(v);
    return (u & 0x80000000u) ? ~u : (u | 0x80000000u);
}

// 3x3 Gaussian [1 2 1; 2 4 2; 1 2 1]/16 on a stride-66 LDS tile, base = top-left
#define GSUM(S, base) \
    ((S[(base)] + 2.0f*S[(base)+1] + S[(base)+2] \
    + 2.0f*S[(base)+66] + 4.0f*S[(base)+67] + 2.0f*S[(base)+68] \
    + S[(base)+132] + 2.0f*S[(base)+133] + S[(base)+134]) * 0.0625f)

__global__ __launch_bounds__(512) void harris_R(const float* __restrict__ x,
                                                float* __restrict__ R) {
    __shared__ float simg[68 * 72];
    __shared__ float sa[66 * 66];
    __shared__ float sb[66 * 66];
    __shared__ float sc[66 * 66];
    const int b   = blockIdx.z;
    const int ty0 = blockIdx.y * TILE;
    const int tx0 = blockIdx.x * TILE;
    const int tid = threadIdx.x;
    const float* x0 = x + (size_t)b * 3 * HH * WW;
    const float* x1 = x0 + HH * WW;
    const float* x2 = x1 + HH * WW;

    // Stage 1: channel-mean image, 68x68 with 2-halo
    for (int i = tid; i < 68 * 68; i += 512) {
        int r = i / 68, c = i - r * 68;
        int gy = ty0 - 2 + r, gx = tx0 - 2 + c;
        float v = 0.0f;
        if ((unsigned)gy < (unsigned)HH && (unsigned)gx < (unsigned)WW) {
            int o = gy * WW + gx;
            v = (x0[o] + x1[o] + x2[o]) / 3.0f;
        }
        simg[r * 72 + c] = v;
    }
    __syncthreads();

    // Stage 2: gradients + products on 66x66 (1-halo for the Gaussian)
    for (int i = tid; i < 66 * 66; i += 512) {
        int r = i / 66, c = i - r * 66;
        const float* p = &simg[r * 72 + c];
        float tl = p[0],   tc = p[1],   tr = p[2];
        float ml = p[72],               mr = p[74];
        float bl = p[144], bc = p[145], br = p[146];
        float dxv = (tr + mr + br) - (tl + ml + bl);
        float dyv = (bl + bc + br) - (tl + tc + tr);
        sa[i] = dxv * dxv;
        sb[i] = dyv * dyv;
        sc[i] = dxv * dyv;
    }
    __syncthreads();

    // Stage 3: Gaussian smooth + Harris response + margin mask
    for (int i = tid; i < TILE * TILE; i += 512) {
        int oy = i >> 6, ox = i & 63;
        int base = oy * 66 + ox;
        float Sxx = GSUM(sa, base);
        float Syy = GSUM(sb, base);
        float Sxy = GSUM(sc, base);
        float det = Sxx * Syy - Sxy * Sxy;
        float trc = Sxx + Syy;
        float Rv  = det - 0.04f * trc * trc;
        int gy = ty0 + oy, gx = tx0 + ox;
        if (gy < 5 || gy > HH - 6 || gx < 5 || gx > WW - 6) Rv = 0.0f;
        R[(size_t)b * (HH * WW) + (size_t)gy * WW + gx] = Rv;
    }
}

__global__ __launch_bounds__(256) void init_k(u32* __restrict__ hist, u32* __restrict__ cnt) {
    int i = blockIdx.x * 256 + threadIdx.x;
    if (i < NB * NBINS) hist[i] = 0u;
    if (i < NB) cnt[i] = 0u;
}

__global__ __launch_bounds__(256) void hist_k(const float* __restrict__ R,
                                              u32* __restrict__ hist) {
    __shared__ u32 lh[NBINS];
    for (int i = threadIdx.x; i < NBINS; i += 256) lh[i] = 0u;
    __syncthreads();
    const int b = blockIdx.y;
    const size_t base = (size_t)b * (HH * WW) + (size_t)blockIdx.x * 16384;
    for (int i = threadIdx.x; i < 16384; i += 256) {
        u32 m = fmap(R[base + i]);
        atomicAdd(&lh[m >> 20], 1u);
    }
    __syncthreads();
    u32* gh = hist + b * NBINS;
    for (int i = threadIdx.x; i < NBINS; i += 256)
        if (lh[i]) atomicAdd(&gh[i], lh[i]);
}

__global__ void select_k(const u32* __restrict__ hist, int* __restrict__ cut) {
    int b = blockIdx.x;
    if (threadIdx.x == 0) {
        const u32* h = hist + b * NBINS;
        u32 s = 0; int t = 0;
        for (int i = NBINS - 1; i >= 0; --i) {
            s += h[i];
            if (s >= KTOP) { t = i; break; }
        }
        cut[b] = t;
    }
}

__global__ __launch_bounds__(256) void compact_k(const float* __restrict__ R,
                                                 const int* __restrict__ cut,
                                                 u32* __restrict__ cnt,
                                                 u64* __restrict__ cand) {
    const int b = blockIdx.y;
    const int t = cut[b];
    const size_t base = (size_t)b * (HH * WW) + (size_t)blockIdx.x * 16384;
    for (int i = threadIdx.x; i < 16384; i += 256) {
        u32 idx = blockIdx.x * 16384 + i;
        u32 m = fmap(R[base + i]);
        if ((int)(m >> 20) >= t) {
            u32 pos = atomicAdd(&cnt[b], 1u);
            if (pos < CAP) cand[(size_t)b * CAP + pos] = ((u64)m << 32) | (u32)(~idx);
        }
    }
}

__global__ __launch_bounds__(1024) void sortout_k(const u32* __restrict__ cnt,
                                                  const u64* __restrict__ cand,
                                                  float* __restrict__ out) {
    __shared__ u64 s[CAP];
    const int b = blockIdx.x;
    u32 n = cnt[b];
    if (n > CAP) n = CAP;
    u32 P = 512;
    while (P < n) P <<= 1;
    for (u32 i = threadIdx.x; i < P; i += 1024)
        s[i] = (i < n) ? cand[(size_t)b * CAP + i] : 0ULL;
    __syncthreads();
    for (u32 size = 2; size <= P; size <<= 1) {
        for (u32 stride = size >> 1; stride > 0; stride >>= 1) {
            for (u32 t = threadIdx.x; t < (P >> 1); t += 1024) {
                u32 i = 2 * t - (t & (stride - 1));
                u32 j = i + stride;
                u64 a = s[i], c = s[j];
                bool desc = ((i & size) == 0);
                if (desc ? (a < c) : (a > c)) { s[i] = c; s[j] = a; }
            }
            __syncthreads();
        }
    }
    if (threadIdx.x < KTOP) {
        u64 k = s[threadIdx.x];
        u32 idx = ~(u32)k;
        u32 row = idx >> 10, col = idx & 1023;
        float rf = ((float)row * (1.0f / 1024.0f) - 0.5f) * 2.0f;
        float cf = ((float)col * (1.0f / 1024.0f) - 0.5f) * 2.0f;
        rf = fminf(fmaxf(rf, -1.0f), 1.0f);
        cf = fminf(fmaxf(cf, -1.0f), 1.0f);
        float* o = out + ((size_t)b * KTOP + threadIdx.x) * 2;
        o[0] = rf;
        o[1] = cf;
    }
}

extern "C" void kernel_launch(void* const* d_in, const int* in_sizes, int n_in,
                              void* d_out, int out_size, void* d_ws, size_t ws_size,
                              hipStream_t stream) {
    const float* x = (const float*)d_in[0];
    float* out = (float*)d_out;
    char* ws = (char*)d_ws;

    // ws layout (bytes):
    //   [0, 64MB)           R         float[16 * 1024 * 1024]
    //   [64MB, +256KB)      hist      u32[16 * 4096]
    //   then cut (64B), cnt (64B), cand u64[16 * 8192]
    float* R   = (float*)ws;
    u32*  hist = (u32*)(ws + 67108864);
    int*  cut  = (int*)(ws + 67371008);
    u32*  cnt  = (u32*)(ws + 67371072);
    u64*  cand = (u64*)(ws + 67371136);

    hipLaunchKernelGGL(init_k, dim3((NB * NBINS + 255) / 256), dim3(256), 0, stream,
                       hist, cnt);
    hipLaunchKernelGGL(harris_R, dim3(WW / TILE, HH / TILE, NB), dim3(512), 0, stream,
                       x, R);
    hipLaunchKernelGGL(hist_k, dim3(64, NB), dim3(256), 0, stream, R, hist);
    hipLaunchKernelGGL(select_k, dim3(NB), dim3(64), 0, stream, hist, cut);
    hipLaunchKernelGGL(compact_k, dim3(64, NB), dim3(256), 0, stream, R, cut, cnt, cand);
    hipLaunchKernelGGL(sortout_k, dim3(NB), dim3(1024), 0, stream, cnt, cand, out);
}

// Round 2
// 259.983 us; speedup vs baseline: 1.2140x; 1.2140x over previous
//
#include <hip/hip_runtime.h>
#include <stdint.h>

#define HH 1024
#define WW 1024
#define NB 16
#define KTOP 512
#define NBINS 4096
#define CAP 8192
#define SW 72   // simg stride (floats)
#define PS 68   // product-array stride (floats)

typedef unsigned long long u64;
typedef unsigned int u32;

__device__ __forceinline__ u32 fmap(float v) {
    u32 u = __float_as_uint(v);
    return (u & 0x80000000u) ? ~u : (u | 0x80000000u);
}

// Fused Harris: channel-mean -> dx,dy -> products -> 3x3 Gaussian -> R -> mapped key m
// Tile: 64x64 outputs. simg covers gy in [ty0-2,ty0+66), gx in [tx0-4,tx0+68) (72 wide, f4-aligned).
// Products cover rows pr in [0,66) (gy = ty0-1+pr), cols p in [0,68) (gx = tx0-1+p).
__global__ __launch_bounds__(512) void harris_R(const float* __restrict__ x,
                                                u32* __restrict__ Rm) {
    __shared__ __align__(16) float simg[68 * SW];
    __shared__ __align__(16) float sa[66 * PS];
    __shared__ __align__(16) float sb[66 * PS];
    __shared__ __align__(16) float sc[66 * PS];
    const int b   = blockIdx.z;
    const int ty0 = blockIdx.y * 64;
    const int tx0 = blockIdx.x * 64;
    const int tid = threadIdx.x;
    const float* x0 = x + (size_t)b * 3 * HH * WW;
    const float* x1 = x0 + HH * WW;
    const float* x2 = x1 + HH * WW;

    // Stage 1: channel-mean into simg, 68 rows x 18 float4 (covers 72 cols)
    for (int g = tid; g < 68 * 18; g += 512) {
        int sy = g / 18, f = g - sy * 18;
        int gy  = ty0 - 2 + sy;
        int gx0 = tx0 - 4 + 4 * f;
        gy  = min(max(gy, 0), HH - 1);        // clamped halo: only feeds masked outputs
        gx0 = min(max(gx0, 0), WW - 4);
        size_t o = (size_t)gy * WW + gx0;
        float4 a = *(const float4*)(x0 + o);
        float4 c = *(const float4*)(x1 + o);
        float4 d = *(const float4*)(x2 + o);
        float4 m;
        m.x = (a.x + c.x + d.x) / 3.0f;
        m.y = (a.y + c.y + d.y) / 3.0f;
        m.z = (a.z + c.z + d.z) / 3.0f;
        m.w = (a.w + c.w + d.w) / 3.0f;
        *(float4*)&simg[sy * SW + 4 * f] = m;
    }
    __syncthreads();

    // Stage 2: gradients + products, rows pr in [0,66), groups of 4 cols (17 groups -> p in [0,68))
    for (int g = tid; g < 66 * 17; g += 512) {
        int pr = g / 17, p4 = g - pr * 17;
        int sxb = 4 * p4;                     // window cols k=0..7 ; px j uses k=j+2..j+4
        const float* r0 = &simg[(pr + 0) * SW + sxb];
        const float* r1 = &simg[(pr + 1) * SW + sxb];
        const float* r2 = &simg[(pr + 2) * SW + sxb];
        float4 r0a = *(const float4*)r0, r0b = *(const float4*)(r0 + 4);
        float4 r1a = *(const float4*)r1, r1b = *(const float4*)(r1 + 4);
        float4 r2a = *(const float4*)r2, r2b = *(const float4*)(r2 + 4);
        float w0[8] = {r0a.x, r0a.y, r0a.z, r0a.w, r0b.x, r0b.y, r0b.z, r0b.w};
        float w1[8] = {r1a.x, r1a.y, r1a.z, r1a.w, r1b.x, r1b.y, r1b.z, r1b.w};
        float w2[8] = {r2a.x, r2a.y, r2a.z, r2a.w, r2b.x, r2b.y, r2b.z, r2b.w};
        float4 va, vb, vc;
        float* pa = (float*)&va; float* pb = (float*)&vb; float* pc = (float*)&vc;
        #pragma unroll
        for (int j = 0; j < 4; ++j) {
            float tl = w0[j + 2], tc = w0[j + 3], tr = w0[j + 4];
            float ml = w1[j + 2],                 mr = w1[j + 4];
            float bl = w2[j + 2], bc = w2[j + 3], br = w2[j + 4];
            float dxv = (tr + mr + br) - (tl + ml + bl);
            float dyv = (bl + bc + br) - (tl + tc + tr);
            pa[j] = dxv * dxv;
            pb[j] = dyv * dyv;
            pc[j] = dxv * dyv;
        }
        int o = pr * PS + 4 * p4;
        *(float4*)&sa[o] = va;
        *(float4*)&sb[o] = vb;
        *(float4*)&sc[o] = vc;
    }
    __syncthreads();

    // Stage 3: 3x3 Gaussian + response + margin mask, 64 rows x 16 float4 groups
    for (int g = tid; g < 64 * 16; g += 512) {
        int oy = g >> 4, ox4 = g & 15;
        int pb0 = 4 * ox4;                    // window k=0..5 ; px j uses k=j..j+2
        float wa[3][8], wb[3][8], wc[3][8];
        #pragma unroll
        for (int r = 0; r < 3; ++r) {
            int o = (oy + r) * PS + pb0;
            float4 ax = *(const float4*)&sa[o], ay = *(const float4*)&sa[o + 4];
            float4 bx = *(const float4*)&sb[o], by = *(const float4*)&sb[o + 4];
            float4 cx = *(const float4*)&sc[o], cy = *(const float4*)&sc[o + 4];
            wa[r][0]=ax.x; wa[r][1]=ax.y; wa[r][2]=ax.z; wa[r][3]=ax.w; wa[r][4]=ay.x; wa[r][5]=ay.y;
            wb[r][0]=bx.x; wb[r][1]=bx.y; wb[r][2]=bx.z; wb[r][3]=bx.w; wb[r][4]=by.x; wb[r][5]=by.y;
            wc[r][0]=cx.x; wc[r][1]=cx.y; wc[r][2]=cx.z; wc[r][3]=cx.w; wc[r][4]=cy.x; wc[r][5]=cy.y;
        }
        uint4 mout;
        u32* mo = (u32*)&mout;
        int gy = ty0 + oy;
        #pragma unroll
        for (int j = 0; j < 4; ++j) {
            float Sxx = (wa[0][j] + 2.0f*wa[0][j+1] + wa[0][j+2]
                       + 2.0f*wa[1][j] + 4.0f*wa[1][j+1] + 2.0f*wa[1][j+2]
                       + wa[2][j] + 2.0f*wa[2][j+1] + wa[2][j+2]) * 0.0625f;
            float Syy = (wb[0][j] + 2.0f*wb[0][j+1] + wb[0][j+2]
                       + 2.0f*wb[1][j] + 4.0f*wb[1][j+1] + 2.0f*wb[1][j+2]
                       + wb[2][j] + 2.0f*wb[2][j+1] + wb[2][j+2]) * 0.0625f;
            float Sxy = (wc[0][j] + 2.0f*wc[0][j+1] + wc[0][j+2]
                       + 2.0f*wc[1][j] + 4.0f*wc[1][j+1] + 2.0f*wc[1][j+2]
                       + wc[2][j] + 2.0f*wc[2][j+1] + wc[2][j+2]) * 0.0625f;
            float det = Sxx * Syy - Sxy * Sxy;
            float trc = Sxx + Syy;
            float Rv  = det - 0.04f * trc * trc;
            int gx = tx0 + 4 * ox4 + j;
            if (gy < 5 || gy > HH - 6 || gx < 5 || gx > WW - 6) Rv = 0.0f;
            mo[j] = fmap(Rv);
        }
        *(uint4*)&Rm[(size_t)b * (HH * WW) + (size_t)gy * WW + tx0 + 4 * ox4] = mout;
    }
}

__global__ __launch_bounds__(256) void hist_k(const u32* __restrict__ Rm,
                                              u32* __restrict__ hist) {
    __shared__ u32 lh[NBINS];
    for (int i = threadIdx.x; i < NBINS; i += 256) lh[i] = 0u;
    __syncthreads();
    const int b = blockIdx.y;
    const uint4* p = (const uint4*)(Rm + (size_t)b * (HH * WW)) + (size_t)blockIdx.x * 4096;
    for (int i = threadIdx.x; i < 4096; i += 256) {
        uint4 v = p[i];
        atomicAdd(&lh[v.x >> 20], 1u);
        atomicAdd(&lh[v.y >> 20], 1u);
        atomicAdd(&lh[v.z >> 20], 1u);
        atomicAdd(&lh[v.w >> 20], 1u);
    }
    __syncthreads();
    u32* gh = hist + b * NBINS;
    for (int i = threadIdx.x; i < NBINS; i += 256)
        if (lh[i]) atomicAdd(&gh[i], lh[i]);
}

// Parallel suffix-scan cutoff selection: one 256-thread block per batch.
__global__ __launch_bounds__(256) void select_k(const u32* __restrict__ hist,
                                                int* __restrict__ cut) {
    __shared__ u32 chunk[256];
    const int b = blockIdx.x;
    const u32* h = hist + b * NBINS;
    const int t = threadIdx.x;
    u32 loc[16];
    u32 s = 0;
    #pragma unroll
    for (int i = 0; i < 16; ++i) { loc[i] = h[t * 16 + i]; s += loc[i]; }
    chunk[t] = s;
    __syncthreads();
    u32 v = s;
    for (int off = 1; off < 256; off <<= 1) {
        u32 add = (t + off < 256) ? chunk[t + off] : 0u;
        __syncthreads();
        v += add;
        chunk[t] = v;
        __syncthreads();
    }
    u32 excl = (t < 255) ? chunk[t + 1] : 0u;
    if (excl < KTOP && v >= KTOP) {          // exactly one thread
        u32 acc = excl;
        #pragma unroll
        for (int i = 15; i >= 0; --i) {
            acc += loc[i];
            if (acc >= KTOP) { cut[b] = t * 16 + i; break; }
        }
    }
}

__global__ __launch_bounds__(256) void compact_k(const u32* __restrict__ Rm,
                                                 const int* __restrict__ cut,
                                                 u32* __restrict__ cnt,
                                                 u64* __restrict__ cand) {
    const int b = blockIdx.y;
    const u32 t = (u32)cut[b];
    const uint4* p = (const uint4*)(Rm + (size_t)b * (HH * WW)) + (size_t)blockIdx.x * 4096;
    u64* cb = cand + (size_t)b * CAP;
    for (int i = threadIdx.x; i < 4096; i += 256) {
        uint4 v = p[i];
        u32 i0 = (u32)(blockIdx.x * 16384 + 4 * i);
        if ((v.x >> 20) >= t) { u32 q = atomicAdd(&cnt[b], 1u); if (q < CAP) cb[q] = ((u64)v.x << 32) | (u32)~(i0 + 0); }
        if ((v.y >> 20) >= t) { u32 q = atomicAdd(&cnt[b], 1u); if (q < CAP) cb[q] = ((u64)v.y << 32) | (u32)~(i0 + 1); }
        if ((v.z >> 20) >= t) { u32 q = atomicAdd(&cnt[b], 1u); if (q < CAP) cb[q] = ((u64)v.z << 32) | (u32)~(i0 + 2); }
        if ((v.w >> 20) >= t) { u32 q = atomicAdd(&cnt[b], 1u); if (q < CAP) cb[q] = ((u64)v.w << 32) | (u32)~(i0 + 3); }
    }
}

__global__ __launch_bounds__(1024) void sortout_k(const u32* __restrict__ cnt,
                                                  const u64* __restrict__ cand,
                                                  float* __restrict__ out) {
    __shared__ u64 s[CAP];
    const int b = blockIdx.x;
    u32 n = cnt[b];
    if (n > CAP) n = CAP;
    u32 P = 512;
    while (P < n) P <<= 1;
    for (u32 i = threadIdx.x; i < P; i += 1024)
        s[i] = (i < n) ? cand[(size_t)b * CAP + i] : 0ULL;
    __syncthreads();
    for (u32 size = 2; size <= P; size <<= 1) {
        for (u32 stride = size >> 1; stride > 0; stride >>= 1) {
            for (u32 t = threadIdx.x; t < (P >> 1); t += 1024) {
                u32 i = 2 * t - (t & (stride - 1));
                u32 j = i + stride;
                u64 a = s[i], c = s[j];
                bool desc = ((i & size) == 0);
                if (desc ? (a < c) : (a > c)) { s[i] = c; s[j] = a; }
            }
            __syncthreads();
        }
    }
    if (threadIdx.x < KTOP) {
        u64 k = s[threadIdx.x];
        u32 idx = ~(u32)k;
        u32 row = idx >> 10, col = idx & 1023;
        float rf = ((float)row * (1.0f / 1024.0f) - 0.5f) * 2.0f;
        float cf = ((float)col * (1.0f / 1024.0f) - 0.5f) * 2.0f;
        rf = fminf(fmaxf(rf, -1.0f), 1.0f);
        cf = fminf(fmaxf(cf, -1.0f), 1.0f);
        float* o = out + ((size_t)b * KTOP + threadIdx.x) * 2;
        o[0] = rf;
        o[1] = cf;
    }
}

extern "C" void kernel_launch(void* const* d_in, const int* in_sizes, int n_in,
                              void* d_out, int out_size, void* d_ws, size_t ws_size,
                              hipStream_t stream) {
    const float* x = (const float*)d_in[0];
    float* out = (float*)d_out;
    char* ws = (char*)d_ws;

    // ws layout (bytes):
    //   [0, 64MB)        Rm    u32[16*1024*1024]   (mapped monotone keys)
    //   [64MB, +256KB)   hist  u32[16*4096]
    //   +64B             cnt   u32[16]
    //   +64B             cut   int[16]
    //   +1MB             cand  u64[16*8192]
    u32* Rm   = (u32*)ws;
    u32* hist = (u32*)(ws + 67108864);
    u32* cnt  = (u32*)(ws + 67108864 + 262144);
    int* cut  = (int*)(ws + 67108864 + 262144 + 64);
    u64* cand = (u64*)(ws + 67108864 + 262144 + 128);

    // clear hist + cnt in one async memset (contiguous)
    hipMemsetAsync(hist, 0, 262144 + 64, stream);

    hipLaunchKernelGGL(harris_R, dim3(WW / 64, HH / 64, NB), dim3(512), 0, stream, x, Rm);
    hipLaunchKernelGGL(hist_k, dim3(64, NB), dim3(256), 0, stream, Rm, hist);
    hipLaunchKernelGGL(select_k, dim3(NB), dim3(256), 0, stream, hist, cut);
    hipLaunchKernelGGL(compact_k, dim3(64, NB), dim3(256), 0, stream, Rm, cut, cnt, cand);
    hipLaunchKernelGGL(sortout_k, dim3(NB), dim3(1024), 0, stream, cnt, cand, out);
}

// Round 3
// 252.585 us; speedup vs baseline: 1.2496x; 1.0293x over previous
//
#include <hip/hip_runtime.h>
#include <stdint.h>

#define HH 1024
#define WW 1024
#define NB 16
#define KTOP 512
#define NBINS 4096
#define CAP 8192
#define SW 72   // simg stride (floats)
#define PS 68   // product-array stride (floats)

typedef unsigned long long u64;
typedef unsigned int u32;

__device__ __forceinline__ u32 fmap(float v) {
    u32 u = __float_as_uint(v);
    return (u & 0x80000000u) ? ~u : (u | 0x80000000u);
}

// Fused Harris + per-batch histogram.
// Tile: 64x64 outputs. simg covers gy in [ty0-2,ty0+66), gx in [tx0-4,tx0+68).
__global__ __launch_bounds__(512) void harris_R(const float* __restrict__ x,
                                                u32* __restrict__ Rm,
                                                u32* __restrict__ hist) {
    __shared__ __align__(16) float simg[68 * SW];
    __shared__ __align__(16) float sa[66 * PS];   // reused as u32 hist[4096] in stage 4
    __shared__ __align__(16) float sb[66 * PS];
    __shared__ __align__(16) float sc[66 * PS];
    const int b   = blockIdx.z;
    const int ty0 = blockIdx.y * 64;
    const int tx0 = blockIdx.x * 64;
    const int tid = threadIdx.x;
    const float* x0 = x + (size_t)b * 3 * HH * WW;
    const float* x1 = x0 + HH * WW;
    const float* x2 = x1 + HH * WW;

    // Stage 1: channel-mean into simg, 68 rows x 18 float4
    for (int g = tid; g < 68 * 18; g += 512) {
        int sy = g / 18, f = g - sy * 18;
        int gy  = ty0 - 2 + sy;
        int gx0 = tx0 - 4 + 4 * f;
        gy  = min(max(gy, 0), HH - 1);        // clamped halo: only feeds masked outputs
        gx0 = min(max(gx0, 0), WW - 4);
        size_t o = (size_t)gy * WW + gx0;
        float4 a = *(const float4*)(x0 + o);
        float4 c = *(const float4*)(x1 + o);
        float4 d = *(const float4*)(x2 + o);
        float4 m;
        m.x = (a.x + c.x + d.x) / 3.0f;
        m.y = (a.y + c.y + d.y) / 3.0f;
        m.z = (a.z + c.z + d.z) / 3.0f;
        m.w = (a.w + c.w + d.w) / 3.0f;
        *(float4*)&simg[sy * SW + 4 * f] = m;
    }
    __syncthreads();

    // Stage 2: gradients + products, rows pr in [0,66), 17 groups of 4 cols
    for (int g = tid; g < 66 * 17; g += 512) {
        int pr = g / 17, p4 = g - pr * 17;
        int sxb = 4 * p4;
        const float* r0 = &simg[(pr + 0) * SW + sxb];
        const float* r1 = &simg[(pr + 1) * SW + sxb];
        const float* r2 = &simg[(pr + 2) * SW + sxb];
        float4 r0a = *(const float4*)r0, r0b = *(const float4*)(r0 + 4);
        float4 r1a = *(const float4*)r1, r1b = *(const float4*)(r1 + 4);
        float4 r2a = *(const float4*)r2, r2b = *(const float4*)(r2 + 4);
        float w0[8] = {r0a.x, r0a.y, r0a.z, r0a.w, r0b.x, r0b.y, r0b.z, r0b.w};
        float w1[8] = {r1a.x, r1a.y, r1a.z, r1a.w, r1b.x, r1b.y, r1b.z, r1b.w};
        float w2[8] = {r2a.x, r2a.y, r2a.z, r2a.w, r2b.x, r2b.y, r2b.z, r2b.w};
        float4 va, vb, vc;
        float* pa = (float*)&va; float* pb = (float*)&vb; float* pc = (float*)&vc;
        #pragma unroll
        for (int j = 0; j < 4; ++j) {
            float tl = w0[j + 2], tc = w0[j + 3], tr = w0[j + 4];
            float ml = w1[j + 2],                 mr = w1[j + 4];
            float bl = w2[j + 2], bc = w2[j + 3], br = w2[j + 4];
            float dxv = (tr + mr + br) - (tl + ml + bl);
            float dyv = (bl + bc + br) - (tl + tc + tr);
            pa[j] = dxv * dxv;
            pb[j] = dyv * dyv;
            pc[j] = dxv * dyv;
        }
        int o = pr * PS + 4 * p4;
        *(float4*)&sa[o] = va;
        *(float4*)&sb[o] = vb;
        *(float4*)&sc[o] = vc;
    }
    __syncthreads();

    // Stage 3: 3x3 Gaussian + response + mask; exactly 2 groups of 4 px per thread.
    u32 keys[8];
    #pragma unroll
    for (int it = 0; it < 2; ++it) {
        int g = tid + it * 512;
        int oy = g >> 4, ox4 = g & 15;
        int pb0 = 4 * ox4;
        float wa[3][8], wb[3][8], wc[3][8];
        #pragma unroll
        for (int r = 0; r < 3; ++r) {
            int o = (oy + r) * PS + pb0;
            float4 ax = *(const float4*)&sa[o], ay = *(const float4*)&sa[o + 4];
            float4 bx = *(const float4*)&sb[o], by = *(const float4*)&sb[o + 4];
            float4 cx = *(const float4*)&sc[o], cy = *(const float4*)&sc[o + 4];
            wa[r][0]=ax.x; wa[r][1]=ax.y; wa[r][2]=ax.z; wa[r][3]=ax.w; wa[r][4]=ay.x; wa[r][5]=ay.y;
            wb[r][0]=bx.x; wb[r][1]=bx.y; wb[r][2]=bx.z; wb[r][3]=bx.w; wb[r][4]=by.x; wb[r][5]=by.y;
            wc[r][0]=cx.x; wc[r][1]=cx.y; wc[r][2]=cx.z; wc[r][3]=cx.w; wc[r][4]=cy.x; wc[r][5]=cy.y;
        }
        uint4 mout;
        u32* mo = (u32*)&mout;
        int gy = ty0 + oy;
        #pragma unroll
        for (int j = 0; j < 4; ++j) {
            float Sxx = (wa[0][j] + 2.0f*wa[0][j+1] + wa[0][j+2]
                       + 2.0f*wa[1][j] + 4.0f*wa[1][j+1] + 2.0f*wa[1][j+2]
                       + wa[2][j] + 2.0f*wa[2][j+1] + wa[2][j+2]) * 0.0625f;
            float Syy = (wb[0][j] + 2.0f*wb[0][j+1] + wb[0][j+2]
                       + 2.0f*wb[1][j] + 4.0f*wb[1][j+1] + 2.0f*wb[1][j+2]
                       + wb[2][j] + 2.0f*wb[2][j+1] + wb[2][j+2]) * 0.0625f;
            float Sxy = (wc[0][j] + 2.0f*wc[0][j+1] + wc[0][j+2]
                       + 2.0f*wc[1][j] + 4.0f*wc[1][j+1] + 2.0f*wc[1][j+2]
                       + wc[2][j] + 2.0f*wc[2][j+1] + wc[2][j+2]) * 0.0625f;
            float det = Sxx * Syy - Sxy * Sxy;
            float trc = Sxx + Syy;
            float Rv  = det - 0.04f * trc * trc;
            int gx = tx0 + 4 * ox4 + j;
            if (gy < 5 || gy > HH - 6 || gx < 5 || gx > WW - 6) Rv = 0.0f;
            mo[j] = fmap(Rv);
            keys[it * 4 + j] = mo[j];
        }
        *(uint4*)&Rm[(size_t)b * (HH * WW) + (size_t)gy * WW + tx0 + 4 * ox4] = mout;
    }
    __syncthreads();

    // Stage 4: per-block histogram in reused LDS, then merge to global.
    u32* sh = (u32*)sa;
    for (int i = tid; i < NBINS; i += 512) sh[i] = 0u;
    __syncthreads();
    #pragma unroll
    for (int j = 0; j < 8; ++j) atomicAdd(&sh[keys[j] >> 20], 1u);
    __syncthreads();
    u32* gh = hist + (size_t)b * NBINS;
    for (int i = tid; i < NBINS; i += 512) {
        u32 v = sh[i];
        if (v) atomicAdd(&gh[i], v);
    }
}

// Parallel suffix-scan cutoff selection: one 256-thread block per batch.
__global__ __launch_bounds__(256) void select_k(const u32* __restrict__ hist,
                                                int* __restrict__ cut) {
    __shared__ u32 chunk[256];
    const int b = blockIdx.x;
    const u32* h = hist + b * NBINS;
    const int t = threadIdx.x;
    u32 loc[16];
    u32 s = 0;
    #pragma unroll
    for (int i = 0; i < 16; ++i) { loc[i] = h[t * 16 + i]; s += loc[i]; }
    chunk[t] = s;
    __syncthreads();
    u32 v = s;
    for (int off = 1; off < 256; off <<= 1) {
        u32 add = (t + off < 256) ? chunk[t + off] : 0u;
        __syncthreads();
        v += add;
        chunk[t] = v;
        __syncthreads();
    }
    u32 excl = (t < 255) ? chunk[t + 1] : 0u;
    if (excl < KTOP && v >= KTOP) {          // exactly one thread
        u32 acc = excl;
        #pragma unroll
        for (int i = 15; i >= 0; --i) {
            acc += loc[i];
            if (acc >= KTOP) { cut[b] = t * 16 + i; break; }
        }
    }
}

// Wave-coalesced compaction: 128 blocks/batch, 8 unrolled uint4 loads/thread,
// one atomicAdd per wave per hit-group via ballot.
__global__ __launch_bounds__(256) void compact_k(const u32* __restrict__ Rm,
                                                 const int* __restrict__ cut,
                                                 u32* __restrict__ cnt,
                                                 u64* __restrict__ cand) {
    const int b = blockIdx.y;
    const u32 t = (u32)cut[b];
    const int lane = threadIdx.x & 63;
    const uint4* p = (const uint4*)(Rm + (size_t)b * (HH * WW)) + (size_t)blockIdx.x * 2048;
    u64* cb = cand + (size_t)b * CAP;

    uint4 v[8];
    #pragma unroll
    for (int it = 0; it < 8; ++it) v[it] = p[it * 256 + threadIdx.x];

    #pragma unroll
    for (int it = 0; it < 8; ++it) {
        u32 i0 = (u32)(blockIdx.x * 8192 + 4 * (it * 256 + threadIdx.x));
        u32 val[4] = {v[it].x, v[it].y, v[it].z, v[it].w};
        #pragma unroll
        for (int c = 0; c < 4; ++c) {
            bool pred = (val[c] >> 20) >= t;
            u64 m = __ballot(pred);
            if (m) {
                int first = __ffsll((unsigned long long)m) - 1;
                u32 base = 0;
                if (lane == first) base = atomicAdd(&cnt[b], (u32)__popcll(m));
                base = __shfl(base, first);
                if (pred) {
                    u32 q = base + (u32)__popcll(m & ((1ull << lane) - 1));
                    if (q < CAP) cb[q] = ((u64)val[c] << 32) | (u32)~(i0 + c);
                }
            }
        }
    }
}

__global__ __launch_bounds__(1024) void sortout_k(const u32* __restrict__ cnt,
                                                  const u64* __restrict__ cand,
                                                  float* __restrict__ out) {
    __shared__ u64 s[CAP];
    const int b = blockIdx.x;
    u32 n = cnt[b];
    if (n > CAP) n = CAP;
    u32 P = 512;
    while (P < n) P <<= 1;
    for (u32 i = threadIdx.x; i < P; i += 1024)
        s[i] = (i < n) ? cand[(size_t)b * CAP + i] : 0ULL;
    __syncthreads();
    for (u32 size = 2; size <= P; size <<= 1) {
        for (u32 stride = size >> 1; stride > 0; stride >>= 1) {
            for (u32 t = threadIdx.x; t < (P >> 1); t += 1024) {
                u32 i = 2 * t - (t & (stride - 1));
                u32 j = i + stride;
                u64 a = s[i], c = s[j];
                bool desc = ((i & size) == 0);
                if (desc ? (a < c) : (a > c)) { s[i] = c; s[j] = a; }
            }
            __syncthreads();
        }
    }
    if (threadIdx.x < KTOP) {
        u64 k = s[threadIdx.x];
        u32 idx = ~(u32)k;
        u32 row = idx >> 10, col = idx & 1023;
        float rf = ((float)row * (1.0f / 1024.0f) - 0.5f) * 2.0f;
        float cf = ((float)col * (1.0f / 1024.0f) - 0.5f) * 2.0f;
        rf = fminf(fmaxf(rf, -1.0f), 1.0f);
        cf = fminf(fmaxf(cf, -1.0f), 1.0f);
        float* o = out + ((size_t)b * KTOP + threadIdx.x) * 2;
        o[0] = rf;
        o[1] = cf;
    }
}

extern "C" void kernel_launch(void* const* d_in, const int* in_sizes, int n_in,
                              void* d_out, int out_size, void* d_ws, size_t ws_size,
                              hipStream_t stream) {
    const float* x = (const float*)d_in[0];
    float* out = (float*)d_out;
    char* ws = (char*)d_ws;

    // ws layout (bytes):
    //   [0, 64MB)        Rm    u32[16*1024*1024]   (mapped monotone keys)
    //   [64MB, +256KB)   hist  u32[16*4096]
    //   +64B             cnt   u32[16]
    //   +64B             cut   int[16]
    //   then             cand  u64[16*8192]
    u32* Rm   = (u32*)ws;
    u32* hist = (u32*)(ws + 67108864);
    u32* cnt  = (u32*)(ws + 67108864 + 262144);
    int* cut  = (int*)(ws + 67108864 + 262144 + 64);
    u64* cand = (u64*)(ws + 67108864 + 262144 + 128);

    // clear hist + cnt in one async memset (contiguous)
    hipMemsetAsync(hist, 0, 262144 + 64, stream);

    hipLaunchKernelGGL(harris_R, dim3(WW / 64, HH / 64, NB), dim3(512), 0, stream,
                       x, Rm, hist);
    hipLaunchKernelGGL(select_k, dim3(NB), dim3(256), 0, stream, hist, cut);
    hipLaunchKernelGGL(compact_k, dim3(128, NB), dim3(256), 0, stream, Rm, cut, cnt, cand);
    hipLaunchKernelGGL(sortout_k, dim3(NB), dim3(1024), 0, stream, cnt, cand, out);
}

// Round 4
// 233.043 us; speedup vs baseline: 1.3544x; 1.0839x over previous
//
#include <hip/hip_runtime.h>
#include <stdint.h>

#define HH 1024
#define WW 1024
#define NB 16
#define KTOP 512
#define NBINS 4096
#define CAP 8192
#define SW 72   // simg stride (floats)
#define PS 68   // product-array stride (floats)

typedef unsigned long long u64;
typedef unsigned int u32;

__device__ __forceinline__ u32 fmap(float v) {
    u32 u = __float_as_uint(v);
    return (u & 0x80000000u) ? ~u : (u | 0x80000000u);
}

// Shared Harris tile computation. All three kernels' users rely on this being
// evaluated with IDENTICAL expressions -> bit-identical keys between passes.
// Computes the 8 keys (2 groups of 4 px) for this thread's tile positions.
// simg/sa/sb/sc are the caller's LDS arrays.
__device__ __forceinline__ void harris_tile_keys(
        const float* __restrict__ x0, const float* __restrict__ x1,
        const float* __restrict__ x2, int ty0, int tx0, int tid,
        float* simg, float* sa, float* sb, float* sc, u32 keys[8]) {
    // Stage 1: channel-mean into simg, 68 rows x 18 float4
    for (int g = tid; g < 68 * 18; g += 512) {
        int sy = g / 18, f = g - sy * 18;
        int gy  = ty0 - 2 + sy;
        int gx0 = tx0 - 4 + 4 * f;
        gy  = min(max(gy, 0), HH - 1);        // clamped halo: only feeds masked outputs
        gx0 = min(max(gx0, 0), WW - 4);
        size_t o = (size_t)gy * WW + gx0;
        float4 a = *(const float4*)(x0 + o);
        float4 c = *(const float4*)(x1 + o);
        float4 d = *(const float4*)(x2 + o);
        float4 m;
        m.x = (a.x + c.x + d.x) / 3.0f;
        m.y = (a.y + c.y + d.y) / 3.0f;
        m.z = (a.z + c.z + d.z) / 3.0f;
        m.w = (a.w + c.w + d.w) / 3.0f;
        *(float4*)&simg[sy * SW + 4 * f] = m;
    }
    __syncthreads();

    // Stage 2: gradients + products, rows pr in [0,66), 17 groups of 4 cols
    for (int g = tid; g < 66 * 17; g += 512) {
        int pr = g / 17, p4 = g - pr * 17;
        int sxb = 4 * p4;
        const float* r0 = &simg[(pr + 0) * SW + sxb];
        const float* r1 = &simg[(pr + 1) * SW + sxb];
        const float* r2 = &simg[(pr + 2) * SW + sxb];
        float4 r0a = *(const float4*)r0, r0b = *(const float4*)(r0 + 4);
        float4 r1a = *(const float4*)r1, r1b = *(const float4*)(r1 + 4);
        float4 r2a = *(const float4*)r2, r2b = *(const float4*)(r2 + 4);
        float w0[8] = {r0a.x, r0a.y, r0a.z, r0a.w, r0b.x, r0b.y, r0b.z, r0b.w};
        float w1[8] = {r1a.x, r1a.y, r1a.z, r1a.w, r1b.x, r1b.y, r1b.z, r1b.w};
        float w2[8] = {r2a.x, r2a.y, r2a.z, r2a.w, r2b.x, r2b.y, r2b.z, r2b.w};
        float4 va, vb, vc;
        float* pa = (float*)&va; float* pb = (float*)&vb; float* pc = (float*)&vc;
        #pragma unroll
        for (int j = 0; j < 4; ++j) {
            float tl = w0[j + 2], tc = w0[j + 3], tr = w0[j + 4];
            float ml = w1[j + 2],                 mr = w1[j + 4];
            float bl = w2[j + 2], bc = w2[j + 3], br = w2[j + 4];
            float dxv = (tr + mr + br) - (tl + ml + bl);
            float dyv = (bl + bc + br) - (tl + tc + tr);
            pa[j] = dxv * dxv;
            pb[j] = dyv * dyv;
            pc[j] = dxv * dyv;
        }
        int o = pr * PS + 4 * p4;
        *(float4*)&sa[o] = va;
        *(float4*)&sb[o] = vb;
        *(float4*)&sc[o] = vc;
    }
    __syncthreads();

    // Stage 3: 3x3 Gaussian + response + mask; exactly 2 groups of 4 px per thread.
    #pragma unroll
    for (int it = 0; it < 2; ++it) {
        int g = tid + it * 512;
        int oy = g >> 4, ox4 = g & 15;
        int pb0 = 4 * ox4;
        float wa[3][8], wb[3][8], wc[3][8];
        #pragma unroll
        for (int r = 0; r < 3; ++r) {
            int o = (oy + r) * PS + pb0;
            float4 ax = *(const float4*)&sa[o], ay = *(const float4*)&sa[o + 4];
            float4 bx = *(const float4*)&sb[o], by = *(const float4*)&sb[o + 4];
            float4 cx = *(const float4*)&sc[o], cy = *(const float4*)&sc[o + 4];
            wa[r][0]=ax.x; wa[r][1]=ax.y; wa[r][2]=ax.z; wa[r][3]=ax.w; wa[r][4]=ay.x; wa[r][5]=ay.y;
            wb[r][0]=bx.x; wb[r][1]=bx.y; wb[r][2]=bx.z; wb[r][3]=bx.w; wb[r][4]=by.x; wb[r][5]=by.y;
            wc[r][0]=cx.x; wc[r][1]=cx.y; wc[r][2]=cx.z; wc[r][3]=cx.w; wc[r][4]=cy.x; wc[r][5]=cy.y;
        }
        int gy = ty0 + oy;
        #pragma unroll
        for (int j = 0; j < 4; ++j) {
            float Sxx = (wa[0][j] + 2.0f*wa[0][j+1] + wa[0][j+2]
                       + 2.0f*wa[1][j] + 4.0f*wa[1][j+1] + 2.0f*wa[1][j+2]
                       + wa[2][j] + 2.0f*wa[2][j+1] + wa[2][j+2]) * 0.0625f;
            float Syy = (wb[0][j] + 2.0f*wb[0][j+1] + wb[0][j+2]
                       + 2.0f*wb[1][j] + 4.0f*wb[1][j+1] + 2.0f*wb[1][j+2]
                       + wb[2][j] + 2.0f*wb[2][j+1] + wb[2][j+2]) * 0.0625f;
            float Sxy = (wc[0][j] + 2.0f*wc[0][j+1] + wc[0][j+2]
                       + 2.0f*wc[1][j] + 4.0f*wc[1][j+1] + 2.0f*wc[1][j+2]
                       + wc[2][j] + 2.0f*wc[2][j+1] + wc[2][j+2]) * 0.0625f;
            float det = Sxx * Syy - Sxy * Sxy;
            float trc = Sxx + Syy;
            float Rv  = det - 0.04f * trc * trc;
            int gx = tx0 + 4 * ox4 + j;
            if (gy < 5 || gy > HH - 6 || gx < 5 || gx > WW - 6) Rv = 0.0f;
            keys[it * 4 + j] = fmap(Rv);
        }
    }
}

// Pass 1: keys -> per-batch histogram + per-tile max. No key materialization.
__global__ __launch_bounds__(512) void harris_R(const float* __restrict__ x,
                                                u32* __restrict__ hist,
                                                u32* __restrict__ tilemax) {
    __shared__ __align__(16) float simg[68 * SW];
    __shared__ __align__(16) float sa[66 * PS];   // reused as u32 hist[4096] afterwards
    __shared__ __align__(16) float sb[66 * PS];
    __shared__ __align__(16) float sc[66 * PS];
    __shared__ u32 wmax[8];
    const int b   = blockIdx.z;
    const int ty0 = blockIdx.y * 64;
    const int tx0 = blockIdx.x * 64;
    const int tid = threadIdx.x;
    const float* x0 = x + (size_t)b * 3 * HH * WW;
    const float* x1 = x0 + HH * WW;
    const float* x2 = x1 + HH * WW;

    u32 keys[8];
    harris_tile_keys(x0, x1, x2, ty0, tx0, tid, simg, sa, sb, sc, keys);

    // per-tile max key
    u32 mx = keys[0];
    #pragma unroll
    for (int j = 1; j < 8; ++j) mx = max(mx, keys[j]);
    #pragma unroll
    for (int off = 32; off > 0; off >>= 1) mx = max(mx, (u32)__shfl_xor((int)mx, off));
    if ((tid & 63) == 0) wmax[tid >> 6] = mx;
    __syncthreads();   // also separates stage-3 reads of sa from the hist reuse below

    // per-block histogram in reused LDS, then merge to global.
    u32* sh = (u32*)sa;
    for (int i = tid; i < NBINS; i += 512) sh[i] = 0u;
    __syncthreads();
    #pragma unroll
    for (int j = 0; j < 8; ++j) atomicAdd(&sh[keys[j] >> 20], 1u);
    __syncthreads();
    u32* gh = hist + (size_t)b * NBINS;
    for (int i = tid; i < NBINS; i += 512) {
        u32 v = sh[i];
        if (v) atomicAdd(&gh[i], v);
    }
    if (tid == 0) {
        u32 m0 = wmax[0];
        #pragma unroll
        for (int w = 1; w < 8; ++w) m0 = max(m0, wmax[w]);
        tilemax[(b << 8) | (blockIdx.y << 4) | blockIdx.x] = m0;
    }
}

// Parallel suffix-scan cutoff selection: one 256-thread block per batch.
__global__ __launch_bounds__(256) void select_k(const u32* __restrict__ hist,
                                                int* __restrict__ cut) {
    __shared__ u32 chunk[256];
    const int b = blockIdx.x;
    const u32* h = hist + b * NBINS;
    const int t = threadIdx.x;
    u32 loc[16];
    u32 s = 0;
    #pragma unroll
    for (int i = 0; i < 16; ++i) { loc[i] = h[t * 16 + i]; s += loc[i]; }
    chunk[t] = s;
    __syncthreads();
    u32 v = s;
    for (int off = 1; off < 256; off <<= 1) {
        u32 add = (t + off < 256) ? chunk[t + off] : 0u;
        __syncthreads();
        v += add;
        chunk[t] = v;
        __syncthreads();
    }
    u32 excl = (t < 255) ? chunk[t + 1] : 0u;
    if (excl < KTOP && v >= KTOP) {          // exactly one thread
        u32 acc = excl;
        #pragma unroll
        for (int i = 15; i >= 0; --i) {
            acc += loc[i];
            if (acc >= KTOP) { cut[b] = t * 16 + i; break; }
        }
    }
}

// Pass 2: recompute only tiles that can contain a hit; ballot-compact hits.
__global__ __launch_bounds__(512) void refine_k(const float* __restrict__ x,
                                                const u32* __restrict__ tilemax,
                                                const int* __restrict__ cut,
                                                u32* __restrict__ cnt,
                                                u64* __restrict__ cand) {
    const int b = blockIdx.z;
    const u32 t = (u32)cut[b];
    const u32 tmax = tilemax[(b << 8) | (blockIdx.y << 4) | blockIdx.x];
    if ((tmax >> 20) < t) return;            // uniform early-exit, no barriers yet

    __shared__ __align__(16) float simg[68 * SW];
    __shared__ __align__(16) float sa[66 * PS];
    __shared__ __align__(16) float sb[66 * PS];
    __shared__ __align__(16) float sc[66 * PS];
    const int ty0 = blockIdx.y * 64;
    const int tx0 = blockIdx.x * 64;
    const int tid = threadIdx.x;
    const float* x0 = x + (size_t)b * 3 * HH * WW;
    const float* x1 = x0 + HH * WW;
    const float* x2 = x1 + HH * WW;

    u32 keys[8];
    harris_tile_keys(x0, x1, x2, ty0, tx0, tid, simg, sa, sb, sc, keys);

    const int lane = tid & 63;
    u64* cb = cand + (size_t)b * CAP;
    #pragma unroll
    for (int it = 0; it < 2; ++it) {
        int g = tid + it * 512;
        int oy = g >> 4, ox4 = g & 15;
        u32 base_idx = (u32)(((ty0 + oy) << 10) | (tx0 + 4 * ox4));
        #pragma unroll
        for (int j = 0; j < 4; ++j) {
            u32 key = keys[it * 4 + j];
            bool pred = (key >> 20) >= t;
            u64 m = __ballot(pred);
            if (m) {
                int first = __ffsll((unsigned long long)m) - 1;
                u32 base = 0;
                if (lane == first) base = atomicAdd(&cnt[b], (u32)__popcll(m));
                base = __shfl(base, first);
                if (pred) {
                    u32 q = base + (u32)__popcll(m & ((1ull << lane) - 1));
                    if (q < CAP) cb[q] = ((u64)key << 32) | (u32)~(base_idx + j);
                }
            }
        }
    }
}

__global__ __launch_bounds__(1024) void sortout_k(const u32* __restrict__ cnt,
                                                  const u64* __restrict__ cand,
                                                  float* __restrict__ out) {
    __shared__ u64 s[CAP];
    const int b = blockIdx.x;
    u32 n = cnt[b];
    if (n > CAP) n = CAP;
    u32 P = 512;
    while (P < n) P <<= 1;
    for (u32 i = threadIdx.x; i < P; i += 1024)
        s[i] = (i < n) ? cand[(size_t)b * CAP + i] : 0ULL;
    __syncthreads();
    for (u32 size = 2; size <= P; size <<= 1) {
        for (u32 stride = size >> 1; stride > 0; stride >>= 1) {
            for (u32 t = threadIdx.x; t < (P >> 1); t += 1024) {
                u32 i = 2 * t - (t & (stride - 1));
                u32 j = i + stride;
                u64 a = s[i], c = s[j];
                bool desc = ((i & size) == 0);
                if (desc ? (a < c) : (a > c)) { s[i] = c; s[j] = a; }
            }
            __syncthreads();
        }
    }
    if (threadIdx.x < KTOP) {
        u64 k = s[threadIdx.x];
        u32 idx = ~(u32)k;
        u32 row = idx >> 10, col = idx & 1023;
        float rf = ((float)row * (1.0f / 1024.0f) - 0.5f) * 2.0f;
        float cf = ((float)col * (1.0f / 1024.0f) - 0.5f) * 2.0f;
        rf = fminf(fmaxf(rf, -1.0f), 1.0f);
        cf = fminf(fmaxf(cf, -1.0f), 1.0f);
        float* o = out + ((size_t)b * KTOP + threadIdx.x) * 2;
        o[0] = rf;
        o[1] = cf;
    }
}

extern "C" void kernel_launch(void* const* d_in, const int* in_sizes, int n_in,
                              void* d_out, int out_size, void* d_ws, size_t ws_size,
                              hipStream_t stream) {
    const float* x = (const float*)d_in[0];
    float* out = (float*)d_out;
    char* ws = (char*)d_ws;

    // ws layout (bytes):
    //   [0, 256KB)       hist     u32[16*4096]
    //   +64B             cnt      u32[16]
    //   +64B             cut      int[16]
    //   +16KB            tilemax  u32[16*256]
    //   then             cand     u64[16*8192]
    u32* hist    = (u32*)ws;
    u32* cnt     = (u32*)(ws + 262144);
    int* cut     = (int*)(ws + 262144 + 64);
    u32* tilemax = (u32*)(ws + 262144 + 128);
    u64* cand    = (u64*)(ws + 262144 + 128 + 16384);

    // clear hist + cnt in one async memset (contiguous)
    hipMemsetAsync(hist, 0, 262144 + 64, stream);

    hipLaunchKernelGGL(harris_R, dim3(16, 16, NB), dim3(512), 0, stream,
                       x, hist, tilemax);
    hipLaunchKernelGGL(select_k, dim3(NB), dim3(256), 0, stream, hist, cut);
    hipLaunchKernelGGL(refine_k, dim3(16, 16, NB), dim3(512), 0, stream,
                       x, tilemax, cut, cnt, cand);
    hipLaunchKernelGGL(sortout_k, dim3(NB), dim3(1024), 0, stream, cnt, cand, out);
}

// Round 5
// 223.517 us; speedup vs baseline: 1.4121x; 1.0426x over previous
//
#include <hip/hip_runtime.h>
#include <stdint.h>

#define HH 1024
#define WW 1024
#define NB 16
#define KTOP 512
#define NBINS 4096
#define SLOT 48      // per-tile candidate slots
#define MINKEEP 32   // per-tile target count above bincut
#define SORTCAP 8192
#define SW 72   // simg stride (floats)
#define PS 68   // product-array stride (floats)

typedef unsigned long long u64;
typedef unsigned int u32;

__device__ __forceinline__ u32 fmap(float v) {
    u32 u = __float_as_uint(v);
    return (u & 0x80000000u) ? ~u : (u | 0x80000000u);
}

// ---------------------------------------------------------------------------
// Shared Harris tile computation (validated bit-exact across rounds 1-4).
// Computes the 8 keys (2 groups of 4 px) for this thread's tile positions.
__device__ __forceinline__ void harris_tile_keys(
        const float* __restrict__ x0, const float* __restrict__ x1,
        const float* __restrict__ x2, int ty0, int tx0, int tid,
        float* simg, float* sa, float* sb, float* sc, u32 keys[8]) {
    // Stage 1: channel-mean into simg, 68 rows x 18 float4
    for (int g = tid; g < 68 * 18; g += 512) {
        int sy = g / 18, f = g - sy * 18;
        int gy  = ty0 - 2 + sy;
        int gx0 = tx0 - 4 + 4 * f;
        gy  = min(max(gy, 0), HH - 1);        // clamped halo: only feeds masked outputs
        gx0 = min(max(gx0, 0), WW - 4);
        size_t o = (size_t)gy * WW + gx0;
        float4 a = *(const float4*)(x0 + o);
        float4 c = *(const float4*)(x1 + o);
        float4 d = *(const float4*)(x2 + o);
        float4 m;
        m.x = (a.x + c.x + d.x) / 3.0f;
        m.y = (a.y + c.y + d.y) / 3.0f;
        m.z = (a.z + c.z + d.z) / 3.0f;
        m.w = (a.w + c.w + d.w) / 3.0f;
        *(float4*)&simg[sy * SW + 4 * f] = m;
    }
    __syncthreads();

    // Stage 2: gradients + products, rows pr in [0,66), 17 groups of 4 cols
    for (int g = tid; g < 66 * 17; g += 512) {
        int pr = g / 17, p4 = g - pr * 17;
        int sxb = 4 * p4;
        const float* r0 = &simg[(pr + 0) * SW + sxb];
        const float* r1 = &simg[(pr + 1) * SW + sxb];
        const float* r2 = &simg[(pr + 2) * SW + sxb];
        float4 r0a = *(const float4*)r0, r0b = *(const float4*)(r0 + 4);
        float4 r1a = *(const float4*)r1, r1b = *(const float4*)(r1 + 4);
        float4 r2a = *(const float4*)r2, r2b = *(const float4*)(r2 + 4);
        float w0[8] = {r0a.x, r0a.y, r0a.z, r0a.w, r0b.x, r0b.y, r0b.z, r0b.w};
        float w1[8] = {r1a.x, r1a.y, r1a.z, r1a.w, r1b.x, r1b.y, r1b.z, r1b.w};
        float w2[8] = {r2a.x, r2a.y, r2a.z, r2a.w, r2b.x, r2b.y, r2b.z, r2b.w};
        float4 va, vb, vc;
        float* pa = (float*)&va; float* pb = (float*)&vb; float* pc = (float*)&vc;
        #pragma unroll
        for (int j = 0; j < 4; ++j) {
            float tl = w0[j + 2], tc = w0[j + 3], tr = w0[j + 4];
            float ml = w1[j + 2],                 mr = w1[j + 4];
            float bl = w2[j + 2], bc = w2[j + 3], br = w2[j + 4];
            float dxv = (tr + mr + br) - (tl + ml + bl);
            float dyv = (bl + bc + br) - (tl + tc + tr);
            pa[j] = dxv * dxv;
            pb[j] = dyv * dyv;
            pc[j] = dxv * dyv;
        }
        int o = pr * PS + 4 * p4;
        *(float4*)&sa[o] = va;
        *(float4*)&sb[o] = vb;
        *(float4*)&sc[o] = vc;
    }
    __syncthreads();

    // Stage 3: 3x3 Gaussian + response + mask; exactly 2 groups of 4 px per thread.
    #pragma unroll
    for (int it = 0; it < 2; ++it) {
        int g = tid + it * 512;
        int oy = g >> 4, ox4 = g & 15;
        int pb0 = 4 * ox4;
        float wa[3][8], wb[3][8], wc[3][8];
        #pragma unroll
        for (int r = 0; r < 3; ++r) {
            int o = (oy + r) * PS + pb0;
            float4 ax = *(const float4*)&sa[o], ay = *(const float4*)&sa[o + 4];
            float4 bx = *(const float4*)&sb[o], by = *(const float4*)&sb[o + 4];
            float4 cx = *(const float4*)&sc[o], cy = *(const float4*)&sc[o + 4];
            wa[r][0]=ax.x; wa[r][1]=ax.y; wa[r][2]=ax.z; wa[r][3]=ax.w; wa[r][4]=ay.x; wa[r][5]=ay.y;
            wb[r][0]=bx.x; wb[r][1]=bx.y; wb[r][2]=bx.z; wb[r][3]=bx.w; wb[r][4]=by.x; wb[r][5]=by.y;
            wc[r][0]=cx.x; wc[r][1]=cx.y; wc[r][2]=cx.z; wc[r][3]=cx.w; wc[r][4]=cy.x; wc[r][5]=cy.y;
        }
        int gy = ty0 + oy;
        #pragma unroll
        for (int j = 0; j < 4; ++j) {
            float Sxx = (wa[0][j] + 2.0f*wa[0][j+1] + wa[0][j+2]
                       + 2.0f*wa[1][j] + 4.0f*wa[1][j+1] + 2.0f*wa[1][j+2]
                       + wa[2][j] + 2.0f*wa[2][j+1] + wa[2][j+2]) * 0.0625f;
            float Syy = (wb[0][j] + 2.0f*wb[0][j+1] + wb[0][j+2]
                       + 2.0f*wb[1][j] + 4.0f*wb[1][j+1] + 2.0f*wb[1][j+2]
                       + wb[2][j] + 2.0f*wb[2][j+1] + wb[2][j+2]) * 0.0625f;
            float Sxy = (wc[0][j] + 2.0f*wc[0][j+1] + wc[0][j+2]
                       + 2.0f*wc[1][j] + 4.0f*wc[1][j+1] + 2.0f*wc[1][j+2]
                       + wc[2][j] + 2.0f*wc[2][j+1] + wc[2][j+2]) * 0.0625f;
            float det = Sxx * Syy - Sxy * Sxy;
            float trc = Sxx + Syy;
            float Rv  = det - 0.04f * trc * trc;
            int gx = tx0 + 4 * ox4 + j;
            if (gy < 5 || gy > HH - 6 || gx < 5 || gx > WW - 6) Rv = 0.0f;
            keys[it * 4 + j] = fmap(Rv);
        }
    }
}

// Exact per-pixel recompute, fallback-only (never taken for non-adversarial data).
__device__ u32 harris_key_at(const float* __restrict__ x0, const float* __restrict__ x1,
                             const float* __restrict__ x2, int gy, int gx) {
    if (gy < 5 || gy > HH - 6 || gx < 5 || gx > WW - 6) return fmap(0.0f);
    float m[5][5];
    #pragma unroll
    for (int r = 0; r < 5; ++r)
        #pragma unroll
        for (int c = 0; c < 5; ++c) {
            size_t o = (size_t)(gy - 2 + r) * WW + (gx - 2 + c);
            m[r][c] = (x0[o] + x1[o] + x2[o]) / 3.0f;
        }
    float a[3][3], bb[3][3], cc[3][3];
    #pragma unroll
    for (int pr = 0; pr < 3; ++pr)
        #pragma unroll
        for (int pc = 0; pc < 3; ++pc) {
            float tl = m[pr][pc],     tc = m[pr][pc+1],     tr = m[pr][pc+2];
            float ml = m[pr+1][pc],                         mr = m[pr+1][pc+2];
            float bl = m[pr+2][pc],   bc = m[pr+2][pc+1],   br = m[pr+2][pc+2];
            float dxv = (tr + mr + br) - (tl + ml + bl);
            float dyv = (bl + bc + br) - (tl + tc + tr);
            a[pr][pc] = dxv * dxv;
            bb[pr][pc] = dyv * dyv;
            cc[pr][pc] = dxv * dyv;
        }
    float Sxx = (a[0][0] + 2.0f*a[0][1] + a[0][2]
               + 2.0f*a[1][0] + 4.0f*a[1][1] + 2.0f*a[1][2]
               + a[2][0] + 2.0f*a[2][1] + a[2][2]) * 0.0625f;
    float Syy = (bb[0][0] + 2.0f*bb[0][1] + bb[0][2]
               + 2.0f*bb[1][0] + 4.0f*bb[1][1] + 2.0f*bb[1][2]
               + bb[2][0] + 2.0f*bb[2][1] + bb[2][2]) * 0.0625f;
    float Sxy = (cc[0][0] + 2.0f*cc[0][1] + cc[0][2]
               + 2.0f*cc[1][0] + 4.0f*cc[1][1] + 2.0f*cc[1][2]
               + cc[2][0] + 2.0f*cc[2][1] + cc[2][2]) * 0.0625f;
    float det = Sxx * Syy - Sxy * Sxy;
    float trc = Sxx + Syy;
    return fmap(det - 0.04f * trc * trc);
}

// suffix_excl over 512 threads' ls values: sum of ls over threads with index > tid.
// Uses wave shuffles + an 8-entry LDS array; contains one barrier (all must call).
__device__ __forceinline__ u32 suffix_excl_512(u32 ls, volatile u32* wsum, int tid) {
    int lane = tid & 63, w = tid >> 6;
    u32 v = ls;
    #pragma unroll
    for (int off = 1; off < 64; off <<= 1) {
        u32 t = (u32)__shfl_down((int)v, off);
        if (lane + off < 64) v += t;
    }
    if (lane == 0) wsum[w] = v;        // wave total
    __syncthreads();
    u32 above = 0;
    #pragma unroll
    for (int i = 0; i < 8; ++i) if (i > w) above += wsum[i];
    return above + (v - ls);
}

// ---------------------------------------------------------------------------
// Pass 1: keys -> global batch hist + per-tile top-<=48 slot list with guard bin.
__global__ __launch_bounds__(512) void harris_k(const float* __restrict__ x,
                                                u32* __restrict__ hist,
                                                u32* __restrict__ hdr,
                                                u64* __restrict__ slots) {
    __shared__ __align__(16) float simg[68 * SW];
    __shared__ __align__(16) float sa[66 * PS];   // reused: u32 hist[4096]
    __shared__ __align__(16) float sb[66 * PS];   // reused: scan scratch
    __shared__ __align__(16) float sc[66 * PS];
    __shared__ u32 s_tloc, s_cnt;
    const int b   = blockIdx.z;
    const int ty0 = blockIdx.y * 64;
    const int tx0 = blockIdx.x * 64;
    const int tid = threadIdx.x;
    const int tile = (b << 8) | (blockIdx.y << 4) | blockIdx.x;
    const float* x0 = x + (size_t)b * 3 * HH * WW;
    const float* x1 = x0 + HH * WW;
    const float* x2 = x1 + HH * WW;

    u32 keys[8];
    harris_tile_keys(x0, x1, x2, ty0, tx0, tid, simg, sa, sb, sc, keys);
    __syncthreads();                       // stage-3 reads of sa/sb/sc done

    // Stage 4: block histogram (LDS) with intra-thread dup pre-merge.
    u32* sh = (u32*)sa;
    for (int i = tid; i < NBINS; i += 512) sh[i] = 0u;
    __syncthreads();
    #pragma unroll
    for (int g2 = 0; g2 < 2; ++g2) {
        u32 b0 = keys[g2*4+0] >> 20, b1 = keys[g2*4+1] >> 20;
        u32 b2 = keys[g2*4+2] >> 20, b3 = keys[g2*4+3] >> 20;
        u32 c0 = 1, c1 = 1, c2 = 1, c3 = 1;
        if (b1 == b0) { c0++; c1 = 0; }
        if (b2 == b0) { c0++; c2 = 0; } else if (c1 && b2 == b1) { c1++; c2 = 0; }
        if (b3 == b0) { c0++; c3 = 0; }
        else if (c1 && b3 == b1) { c1++; c3 = 0; }
        else if (c2 && b3 == b2) { c2++; c3 = 0; }
        atomicAdd(&sh[b0], c0);
        if (c1) atomicAdd(&sh[b1], c1);
        if (c2) atomicAdd(&sh[b2], c2);
        if (c3) atomicAdd(&sh[b3], c3);
    }
    __syncthreads();

    // Stage 5: merge to global hist + find tile-local bincut (suffix >= MINKEEP).
    u32 lv[8]; u32 ls = 0;
    #pragma unroll
    for (int i = 0; i < 8; ++i) { lv[i] = sh[tid * 8 + i]; ls += lv[i]; }
    u32* gh = hist + (size_t)b * NBINS;
    #pragma unroll
    for (int i = 0; i < 8; ++i) if (lv[i]) atomicAdd(&gh[tid * 8 + i], lv[i]);

    u32 excl = suffix_excl_512(ls, (volatile u32*)sb, tid);   // has barrier
    if (tid == 0) s_cnt = 0;
    if (excl < MINKEEP && excl + ls >= MINKEEP) {   // exactly one thread
        u32 acc = excl, tbin = 0, suf = 0;
        for (int i = 7; i >= 0; --i) {
            acc += lv[i];
            if (acc >= MINKEEP) { tbin = (u32)(tid * 8 + i); suf = acc; break; }
        }
        s_tloc = (suf > SLOT) ? tbin + 1 : tbin;    // keep count <= SLOT
    }
    __syncthreads();
    const u32 tloc = s_tloc;

    // Stage 6: ballot-compact keys with bin >= tloc into the tile slot list.
    const int lane = tid & 63;
    u64* slot = slots + (size_t)tile * SLOT;
    #pragma unroll
    for (int it = 0; it < 2; ++it) {
        int g = tid + it * 512;
        int oy = g >> 4, ox4 = g & 15;
        u32 bidx = (u32)(((ty0 + oy) << 10) | (tx0 + 4 * ox4));
        #pragma unroll
        for (int j = 0; j < 4; ++j) {
            u32 key = keys[it * 4 + j];
            bool pred = (key >> 20) >= tloc;
            u64 m = __ballot(pred);
            if (m) {
                int first = __ffsll((unsigned long long)m) - 1;
                u32 base = 0;
                if (lane == first) base = atomicAdd(&s_cnt, (u32)__popcll(m));
                base = __shfl(base, first);
                if (pred) {
                    u32 q = base + (u32)__popcll(m & ((1ull << lane) - 1));
                    if (q < SLOT) slot[q] = ((u64)key << 32) | (u32)~(bidx + j);
                }
            }
        }
    }
    __syncthreads();
    if (tid == 0) {
        u32 c = s_cnt;
        // overflow safety: force fallback if slots overflowed (cannot happen by construction)
        hdr[tile] = (c > SLOT) ? 4097u : ((c << 16) | tloc);
    }
}

// ---------------------------------------------------------------------------
// Pass 2 (per batch): cutoff scan + gather + (exact fallback) + sort + output.
__global__ __launch_bounds__(512) void finish_k(const float* __restrict__ x,
                                                const u32* __restrict__ hist,
                                                const u32* __restrict__ hdr,
                                                const u64* __restrict__ slots,
                                                float* __restrict__ out) {
    __shared__ u64 sbuf[SORTCAP];        // 64 KB sort buffer
    __shared__ u32 shd[256];
    __shared__ u32 wsum[8];
    __shared__ u32 s_cut, s_n;
    const int b = blockIdx.x;
    const int tid = threadIdx.x;
    const float* x0 = x + (size_t)b * 3 * HH * WW;
    const float* x1 = x0 + HH * WW;
    const float* x2 = x1 + HH * WW;

    // Phase 0: per-batch cutoff bin (largest bin with suffix >= KTOP).
    const u32* gh = hist + (size_t)b * NBINS;
    u32 lv[8]; u32 ls = 0;
    #pragma unroll
    for (int i = 0; i < 8; ++i) { lv[i] = gh[tid * 8 + i]; ls += lv[i]; }
    if (tid < 256) shd[tid] = hdr[b * 256 + tid];
    if (tid == 0) s_n = 0;
    u32 excl = suffix_excl_512(ls, wsum, tid);      // has barrier
    if (excl < KTOP && excl + ls >= KTOP) {         // exactly one thread
        u32 acc = excl;
        for (int i = 7; i >= 0; --i) {
            acc += lv[i];
            if (acc >= KTOP) { s_cut = (u32)(tid * 8 + i); break; }
        }
    }
    __syncthreads();
    const u32 cut = s_cut;

    // Phase 1: gather candidates from per-tile slot lists.
    for (int e = tid; e < 256 * SLOT; e += 512) {
        int tl = e / SLOT, i = e - tl * SLOT;
        u32 h = shd[tl];
        u32 bc = h & 0xFFFFu, cnt = h >> 16;
        if (bc <= cut && (u32)i < cnt) {
            u64 en = slots[(size_t)(b * 256 + tl) * SLOT + i];
            if ((u32)(en >> 52) >= cut) {
                u32 q = atomicAdd(&s_n, 1u);
                if (q < SORTCAP) sbuf[q] = en;
            }
        }
    }
    __syncthreads();

    // Phase 2: exact fallback for tiles whose guard failed (expected: none).
    for (int tl = 0; tl < 256; ++tl) {
        if ((shd[tl] & 0xFFFFu) <= cut) continue;        // uniform branch
        int ty0 = (tl >> 4) * 64, tx0 = (tl & 15) * 64;
        #pragma unroll
        for (int j = 0; j < 8; ++j) {
            int p = tid * 8 + j;
            int gy = ty0 + (p >> 6), gx = tx0 + (p & 63);
            u32 key = harris_key_at(x0, x1, x2, gy, gx);
            if ((key >> 20) >= cut) {
                u32 q = atomicAdd(&s_n, 1u);
                if (q < SORTCAP) sbuf[q] = ((u64)key << 32) | (u32)~((gy << 10) | gx);
            }
        }
    }
    __syncthreads();

    // Phase 3: bitonic sort (descending) + output.
    u32 n = s_n;
    if (n > SORTCAP) n = SORTCAP;
    u32 P = 512;
    while (P < n) P <<= 1;
    for (u32 i = n + tid; i < P; i += 512) sbuf[i] = 0ULL;
    __syncthreads();
    for (u32 size = 2; size <= P; size <<= 1) {
        for (u32 stride = size >> 1; stride > 0; stride >>= 1) {
            for (u32 t = tid; t < (P >> 1); t += 512) {
                u32 i = 2 * t - (t & (stride - 1));
                u32 j = i + stride;
                u64 a = sbuf[i], c = sbuf[j];
                bool desc = ((i & size) == 0);
                if (desc ? (a < c) : (a > c)) { sbuf[i] = c; sbuf[j] = a; }
            }
            __syncthreads();
        }
    }
    {
        u64 k = sbuf[tid];
        u32 idx = ~(u32)k;
        u32 row = idx >> 10, col = idx & 1023;
        float rf = ((float)row * (1.0f / 1024.0f) - 0.5f) * 2.0f;
        float cf = ((float)col * (1.0f / 1024.0f) - 0.5f) * 2.0f;
        rf = fminf(fmaxf(rf, -1.0f), 1.0f);
        cf = fminf(fmaxf(cf, -1.0f), 1.0f);
        float* o = out + ((size_t)b * KTOP + tid) * 2;
        o[0] = rf;
        o[1] = cf;
    }
}

extern "C" void kernel_launch(void* const* d_in, const int* in_sizes, int n_in,
                              void* d_out, int out_size, void* d_ws, size_t ws_size,
                              hipStream_t stream) {
    const float* x = (const float*)d_in[0];
    float* out = (float*)d_out;
    char* ws = (char*)d_ws;

    // ws layout (bytes):
    //   [0, 256KB)        hist   u32[16*4096]
    //   [256KB, +16KB)    hdr    u32[4096]        (count<<16 | bincut per tile)
    //   [+, +1.5MB)       slots  u64[4096*48]
    u32* hist  = (u32*)ws;
    u32* hdr   = (u32*)(ws + 262144);
    u64* slots = (u64*)(ws + 262144 + 16384);

    hipMemsetAsync(hist, 0, 262144, stream);
    hipLaunchKernelGGL(harris_k, dim3(16, 16, NB), dim3(512), 0, stream,
                       x, hist, hdr, slots);
    hipLaunchKernelGGL(finish_k, dim3(NB), dim3(512), 0, stream,
                       x, hist, hdr, slots, out);
}

// Round 7
// 214.821 us; speedup vs baseline: 1.4693x; 1.0405x over previous
//
#include <hip/hip_runtime.h>
#include <stdint.h>

#define HH 1024
#define WW 1024
#define NB 16
#define KTOP 512
#define NBINS 4096
#define CAP 8192
#define ROWS 16          // output rows per wave-chunk

typedef unsigned long long u64;
typedef unsigned int u32;

__device__ __forceinline__ u32 fmap(float v) {
    u32 u = __float_as_uint(v);
    return (u & 0x80000000u) ? ~u : (u | 0x80000000u);
}
// contraction-proof scalar ops: guarantee bit-identical trees across kernels
__device__ __forceinline__ float fadd(float a, float b){ return __fadd_rn(a,b); }
__device__ __forceinline__ float fsub(float a, float b){ return __fsub_rn(a,b); }
__device__ __forceinline__ float fmul(float a, float b){ return __fmul_rn(a,b); }
__device__ __forceinline__ float add3(float a, float b, float c){ return fadd(fadd(a,b),c); }
// channel mean: IEEE division by 3 — matches rounds 1-5's validated tree
__device__ __forceinline__ float mean3(float a, float b, float c){
    return __fdiv_rn(add3(a,b,c), 3.0f);
}

__device__ __forceinline__ float g9(float w00,float w01,float w02,
                                    float w10,float w11,float w12,
                                    float w20,float w21,float w22){
    float s = fadd(w00, fmul(2.0f,w01));
    s = fadd(s, w02);
    s = fadd(s, fmul(2.0f,w10));
    s = fadd(s, fmul(4.0f,w11));
    s = fadd(s, fmul(2.0f,w12));
    s = fadd(s, w20);
    s = fadd(s, fmul(2.0f,w21));
    s = fadd(s, w22);
    return fmul(s, 0.0625f);
}
__device__ __forceinline__ u32 respkey(float Sxx,float Syy,float Sxy,bool masked){
    float det = fsub(fmul(Sxx,Syy), fmul(Sxy,Sxy));
    float tr  = fadd(Sxx,Syy);
    float R   = fsub(det, fmul(fmul(0.04f,tr),tr));
    if (masked) R = 0.0f;
    return fmap(R);
}

__device__ __forceinline__ float4 vmean(float4 a, float4 b, float4 c){
    return make_float4(mean3(a.x,b.x,c.x), mean3(a.y,b.y,c.y),
                       mean3(a.z,b.z,c.z), mean3(a.w,b.w,c.w));
}
__device__ __forceinline__ float4 vadd3(float4 a, float4 b, float4 c){
    return make_float4(add3(a.x,b.x,c.x), add3(a.y,b.y,c.y),
                       add3(a.z,b.z,c.z), add3(a.w,b.w,c.w));
}
__device__ __forceinline__ float4 vsub(float4 a, float4 b){
    return make_float4(fsub(a.x,b.x), fsub(a.y,b.y), fsub(a.z,b.z), fsub(a.w,b.w));
}
__device__ __forceinline__ float4 vmul(float4 a, float4 b){
    return make_float4(fmul(a.x,b.x), fmul(a.y,b.y), fmul(a.z,b.z), fmul(a.w,b.w));
}
// value at col-1 per slot (shift right in memory order); edge fixes lane 0
__device__ __forceinline__ float4 shl1(float4 v, float edge, int lane){
    float w = __shfl_up(v.w, 1);
    if (lane == 0) w = edge;
    return make_float4(w, v.x, v.y, v.z);
}
// value at col+1 per slot; edge fixes lane 63
__device__ __forceinline__ float4 shr1(float4 v, float edge, int lane){
    float e = __shfl_down(v.x, 1);
    if (lane == 63) e = edge;
    return make_float4(v.y, v.z, v.w, e);
}

// ---------------------------------------------------------------------------
// Pass A: register-streaming Harris. One wave = 256-px strip x 16 output rows.
// No LDS, no barriers. Writes per-(row,64px) granule max key only.
__global__ __launch_bounds__(256) void harris_a(const float* __restrict__ x,
                                                u32* __restrict__ gmax) {
    const int b     = blockIdx.y;
    const int task  = blockIdx.x * 4 + (threadIdx.x >> 6);
    const int lane  = threadIdx.x & 63;
    const int strip = task & 3;
    const int y0    = (task >> 2) * ROWS;
    const int sx    = strip * 256;
    const int cx    = sx + 4 * lane;
    const int hx    = (lane < 32) ? max(sx - 4, 0) : min(sx + 256, WW - 4);
    const float* p0 = x + (size_t)b * 3 * HH * WW;
    const float* p1 = p0 + HH * WW;
    const float* p2 = p1 + HH * WW;

    float4 z4 = make_float4(0.f,0.f,0.f,0.f);
    float4 m0=z4,m1=z4,m2=z4, mh0=z4,mh1=z4,mh2=z4, h0=z4,h1=z4,h2=z4;
    float he0=0.f,he1=0.f,he2=0.f;
    float4 xx0=z4,xx1=z4,xx2=z4, yy0=z4,yy1=z4,yy2=z4, xy0=z4,xy1=z4,xy2=z4;
    float exx0=0.f,exx1=0.f,exx2=0.f, eyy0=0.f,eyy1=0.f,eyy2=0.f, exy0=0.f,exy1=0.f,exy2=0.f;

    #pragma unroll
    for (int t = 0; t < ROWS + 4; ++t) {
        // roll mean/h state
        m0=m1; m1=m2; mh0=mh1; mh1=mh2; h0=h1; h1=h2; he0=he1; he1=he2;
        int ym = min(max(y0 - 2 + t, 0), HH - 1);
        size_t ro = (size_t)ym * WW;
        float4 a0 = *(const float4*)(p0 + ro + cx);
        float4 a1 = *(const float4*)(p1 + ro + cx);
        float4 a2 = *(const float4*)(p2 + ro + cx);
        m2 = vmean(a0, a1, a2);
        float4 b0 = *(const float4*)(p0 + ro + hx);
        float4 b1 = *(const float4*)(p1 + ro + hx);
        float4 b2 = *(const float4*)(p2 + ro + hx);
        mh2 = vmean(b0, b1, b2);
        // horizontal sums of this mean row
        float4 m2l = shl1(m2, mh2.w, lane);
        float4 m2r = shr1(m2, mh2.x, lane);
        h2  = vadd3(m2l, m2, m2r);
        he2 = (lane < 32) ? add3(mh2.z, mh2.w, m2.x) : add3(m2.w, mh2.x, mh2.y);

        if (t >= 2) {
            // products row p = ym-1 (mean rows m0,m1,m2 = p-1,p,p+1)
            xx0=xx1; xx1=xx2; yy0=yy1; yy1=yy2; xy0=xy1; xy1=xy2;
            exx0=exx1; exx1=exx2; eyy0=eyy1; eyy1=eyy2; exy0=exy1; exy1=exy2;
            float4 s  = vadd3(m0, m1, m2);
            float4 sh = vadd3(mh0, mh1, mh2);
            float4 sl = shl1(s, sh.w, lane);
            float4 sr = shr1(s, sh.x, lane);
            float4 dx = vsub(sr, sl);
            float4 dy = vsub(h2, h0);
            xx2 = vmul(dx, dx); yy2 = vmul(dy, dy); xy2 = vmul(dx, dy);
            float dxe = (lane < 32) ? fsub(s.x, sh.z) : fsub(sh.y, s.w);
            float dye = fsub(he2, he0);
            exx2 = fmul(dxe, dxe); eyy2 = fmul(dye, dye); exy2 = fmul(dxe, dye);
        }
        if (t >= 4) {
            int y = y0 + t - 4;
            bool rowm = (y < 5) || (y > HH - 6);
            float4 xxl0 = shl1(xx0, exx0, lane), xxr0 = shr1(xx0, exx0, lane);
            float4 xxl1 = shl1(xx1, exx1, lane), xxr1 = shr1(xx1, exx1, lane);
            float4 xxl2 = shl1(xx2, exx2, lane), xxr2 = shr1(xx2, exx2, lane);
            float4 yyl0 = shl1(yy0, eyy0, lane), yyr0 = shr1(yy0, eyy0, lane);
            float4 yyl1 = shl1(yy1, eyy1, lane), yyr1 = shr1(yy1, eyy1, lane);
            float4 yyl2 = shl1(yy2, eyy2, lane), yyr2 = shr1(yy2, eyy2, lane);
            float4 xyl0 = shl1(xy0, exy0, lane), xyr0 = shr1(xy0, exy0, lane);
            float4 xyl1 = shl1(xy1, exy1, lane), xyr1 = shr1(xy1, exy1, lane);
            float4 xyl2 = shl1(xy2, exy2, lane), xyr2 = shr1(xy2, exy2, lane);

            u32 k[4];
            {
                float Sxx, Syy, Sxy; int gx; bool mk;
                Sxx = g9(xxl0.x,xx0.x,xxr0.x, xxl1.x,xx1.x,xxr1.x, xxl2.x,xx2.x,xxr2.x);
                Syy = g9(yyl0.x,yy0.x,yyr0.x, yyl1.x,yy1.x,yyr1.x, yyl2.x,yy2.x,yyr2.x);
                Sxy = g9(xyl0.x,xy0.x,xyr0.x, xyl1.x,xy1.x,xyr1.x, xyl2.x,xy2.x,xyr2.x);
                gx = cx + 0; mk = rowm || (gx < 5) || (gx > WW - 6);
                k[0] = respkey(Sxx, Syy, Sxy, mk);
                Sxx = g9(xxl0.y,xx0.y,xxr0.y, xxl1.y,xx1.y,xxr1.y, xxl2.y,xx2.y,xxr2.y);
                Syy = g9(yyl0.y,yy0.y,yyr0.y, yyl1.y,yy1.y,yyr1.y, yyl2.y,yy2.y,yyr2.y);
                Sxy = g9(xyl0.y,xy0.y,xyr0.y, xyl1.y,xy1.y,xyr1.y, xyl2.y,xy2.y,xyr2.y);
                gx = cx + 1; mk = rowm || (gx < 5) || (gx > WW - 6);
                k[1] = respkey(Sxx, Syy, Sxy, mk);
                Sxx = g9(xxl0.z,xx0.z,xxr0.z, xxl1.z,xx1.z,xxr1.z, xxl2.z,xx2.z,xxr2.z);
                Syy = g9(yyl0.z,yy0.z,yyr0.z, yyl1.z,yy1.z,yyr1.z, yyl2.z,yy2.z,yyr2.z);
                Sxy = g9(xyl0.z,xy0.z,xyr0.z, xyl1.z,xy1.z,xyr1.z, xyl2.z,xy2.z,xyr2.z);
                gx = cx + 2; mk = rowm || (gx < 5) || (gx > WW - 6);
                k[2] = respkey(Sxx, Syy, Sxy, mk);
                Sxx = g9(xxl0.w,xx0.w,xxr0.w, xxl1.w,xx1.w,xxr1.w, xxl2.w,xx2.w,xxr2.w);
                Syy = g9(yyl0.w,yy0.w,yyr0.w, yyl1.w,yy1.w,yyr1.w, yyl2.w,yy2.w,yyr2.w);
                Sxy = g9(xyl0.w,xy0.w,xyr0.w, xyl1.w,xy1.w,xyr1.w, xyl2.w,xy2.w,xyr2.w);
                gx = cx + 3; mk = rowm || (gx < 5) || (gx > WW - 6);
                k[3] = respkey(Sxx, Syy, Sxy, mk);
            }
            u32 km = max(max(k[0], k[1]), max(k[2], k[3]));
            #pragma unroll
            for (int off = 1; off < 16; off <<= 1)
                km = max(km, (u32)__shfl_xor((int)km, off));
            if ((lane & 15) == 0)
                gmax[((size_t)b << 14) | ((size_t)y << 4) | (u32)(strip * 4 + (lane >> 4))] = km;
        }
    }
}

// ---------------------------------------------------------------------------
// Pass B (per batch): bin 16K granule maxes, pick largest bin with
// granule-suffix >= KTOP (sound cutoff), compact qualifying granule ids.
__global__ __launch_bounds__(512) void select_b(const u32* __restrict__ gmax,
                                                u32* __restrict__ glist,
                                                u32* __restrict__ gcount,
                                                u32* __restrict__ cutb) {
    __shared__ u32 hist[NBINS];
    __shared__ u32 wsum[8];
    __shared__ u32 s_cut, s_n;
    const int b = blockIdx.x;
    const int tid = threadIdx.x;
    const u32* gm = gmax + ((size_t)b << 14);
    u32 val[32];
    #pragma unroll
    for (int j = 0; j < 8; ++j) {
        uint4 v = ((const uint4*)gm)[tid + j * 512];
        val[j*4+0]=v.x; val[j*4+1]=v.y; val[j*4+2]=v.z; val[j*4+3]=v.w;
    }
    for (int i = tid; i < NBINS; i += 512) hist[i] = 0u;
    if (tid == 0) s_n = 0u;
    __syncthreads();
    #pragma unroll
    for (int j = 0; j < 32; ++j) atomicAdd(&hist[val[j] >> 20], 1u);
    __syncthreads();
    u32 lv[8], ls = 0;
    #pragma unroll
    for (int i = 0; i < 8; ++i) { lv[i] = hist[tid*8+i]; ls += lv[i]; }
    const int lane = tid & 63, w = tid >> 6;
    u32 v = ls;
    #pragma unroll
    for (int off = 1; off < 64; off <<= 1) {
        u32 t2 = (u32)__shfl_down((int)v, off);
        if (lane + off < 64) v += t2;
    }
    if (lane == 0) wsum[w] = v;
    __syncthreads();
    u32 excl = v - ls;
    #pragma unroll
    for (int i = 0; i < 8; ++i) if (i > w) excl += wsum[i];
    if (excl < KTOP && excl + ls >= KTOP) {       // exactly one thread
        u32 acc = excl;
        #pragma unroll
        for (int i = 7; i >= 0; --i) {
            acc += lv[i];
            if (acc >= KTOP) { s_cut = (u32)(tid*8 + i); break; }
        }
    }
    __syncthreads();
    const u32 cut = s_cut;
    u32* gl = glist + ((size_t)b << 14);
    #pragma unroll
    for (int j = 0; j < 8; ++j)
        #pragma unroll
        for (int kk = 0; kk < 4; ++kk) {
            u32 gv = val[j*4+kk];
            if ((gv >> 20) >= cut) {
                u32 q = atomicAdd(&s_n, 1u);
                gl[q] = (u32)(j*2048 + 4*tid + kk);
            }
        }
    __syncthreads();
    if (tid == 0) { gcount[b] = s_n; cutb[b] = cut; }
}

// ---------------------------------------------------------------------------
// Exact per-pixel recompute: identical _rn expression trees as harris_a.
__device__ __forceinline__ u32 harris_px(const float* __restrict__ p0,
                                         const float* __restrict__ p1,
                                         const float* __restrict__ p2,
                                         int gy, int gx) {
    if (gy < 5 || gy > HH - 6 || gx < 5 || gx > WW - 6) return 0x80000000u;
    float m[5][5];
    #pragma unroll
    for (int r = 0; r < 5; ++r)
        #pragma unroll
        for (int c = 0; c < 5; ++c) {
            size_t o = (size_t)(gy - 2 + r) * WW + (gx - 2 + c);
            m[r][c] = mean3(p0[o], p1[o], p2[o]);
        }
    float pxx[3][3], pyy[3][3], pxy[3][3];
    #pragma unroll
    for (int pr = 0; pr < 3; ++pr) {
        float s[5], ht[3], hb[3];
        #pragma unroll
        for (int c = 0; c < 5; ++c) s[c] = add3(m[pr][c], m[pr+1][c], m[pr+2][c]);
        #pragma unroll
        for (int c = 0; c < 3; ++c) {
            ht[c] = add3(m[pr][c],   m[pr][c+1],   m[pr][c+2]);
            hb[c] = add3(m[pr+2][c], m[pr+2][c+1], m[pr+2][c+2]);
        }
        #pragma unroll
        for (int pc = 0; pc < 3; ++pc) {
            float dx = fsub(s[pc+2], s[pc]);
            float dy = fsub(hb[pc], ht[pc]);
            pxx[pr][pc] = fmul(dx, dx);
            pyy[pr][pc] = fmul(dy, dy);
            pxy[pr][pc] = fmul(dx, dy);
        }
    }
    float Sxx = g9(pxx[0][0],pxx[0][1],pxx[0][2],pxx[1][0],pxx[1][1],pxx[1][2],pxx[2][0],pxx[2][1],pxx[2][2]);
    float Syy = g9(pyy[0][0],pyy[0][1],pyy[0][2],pyy[1][0],pyy[1][1],pyy[1][2],pyy[2][0],pyy[2][1],pyy[2][2]);
    float Sxy = g9(pxy[0][0],pxy[0][1],pxy[0][2],pxy[1][0],pxy[1][1],pxy[1][2],pxy[2][0],pxy[2][1],pxy[2][2]);
    return respkey(Sxx, Syy, Sxy, false);
}

// Pass C: recompute surviving granules (64px x 1row each), ballot-compact hits.
__global__ __launch_bounds__(256) void refine_c(const float* __restrict__ x,
                                                const u32* __restrict__ glist,
                                                const u32* __restrict__ gcount,
                                                const u32* __restrict__ cutb,
                                                u32* __restrict__ cnt,
                                                u64* __restrict__ cand) {
    const int b = blockIdx.y;
    const u32 gc  = gcount[b];
    const u32 cut = cutb[b];
    const int wv = threadIdx.x >> 6, lane = threadIdx.x & 63;
    const float* p0 = x + (size_t)b * 3 * HH * WW;
    const float* p1 = p0 + HH * WW;
    const float* p2 = p1 + HH * WW;
    u64* cb = cand + (size_t)b * CAP;
    const u32* gl = glist + ((size_t)b << 14);
    for (u32 i = blockIdx.x * 4 + wv; i < gc; i += 128) {
        u32 gid = gl[i];
        int gy = (int)(gid >> 4);
        int gx = (int)((gid & 15u) << 6) + lane;
        u32 key = harris_px(p0, p1, p2, gy, gx);
        bool pred = (key >> 20) >= cut;
        u64 mball = __ballot(pred);
        if (mball) {
            int first = __ffsll((unsigned long long)mball) - 1;
            u32 base = 0;
            if (lane == first) base = atomicAdd(&cnt[b], (u32)__popcll(mball));
            base = __shfl(base, first);
            if (pred) {
                u32 q = base + (u32)__popcll(mball & ((1ull << lane) - 1));
                if (q < CAP) cb[q] = ((u64)key << 32) | (u32)~((u32)(gy << 10) | (u32)gx);
            }
        }
    }
}

// ---------------------------------------------------------------------------
// Pass D: per-batch bitonic sort + coords.
__global__ __launch_bounds__(1024) void sort_d(const u32* __restrict__ cnt,
                                               const u64* __restrict__ cand,
                                               float* __restrict__ out) {
    __shared__ u64 s[CAP];
    const int b = blockIdx.x;
    u32 n = cnt[b];
    if (n > CAP) n = CAP;
    u32 P = 512;
    while (P < n) P <<= 1;
    for (u32 i = threadIdx.x; i < P; i += 1024)
        s[i] = (i < n) ? cand[(size_t)b * CAP + i] : 0ULL;
    __syncthreads();
    for (u32 size = 2; size <= P; size <<= 1) {
        for (u32 stride = size >> 1; stride > 0; stride >>= 1) {
            for (u32 t = threadIdx.x; t < (P >> 1); t += 1024) {
                u32 i = 2 * t - (t & (stride - 1));
                u32 j = i + stride;
                u64 a = s[i], c = s[j];
                bool desc = ((i & size) == 0);
                if (desc ? (a < c) : (a > c)) { s[i] = c; s[j] = a; }
            }
            __syncthreads();
        }
    }
    if (threadIdx.x < KTOP) {
        u64 k = s[threadIdx.x];
        u32 idx = ~(u32)k;
        u32 row = idx >> 10, col = idx & 1023;
        float rf = ((float)row * (1.0f / 1024.0f) - 0.5f) * 2.0f;
        float cf = ((float)col * (1.0f / 1024.0f) - 0.5f) * 2.0f;
        rf = fminf(fmaxf(rf, -1.0f), 1.0f);
        cf = fminf(fmaxf(cf, -1.0f), 1.0f);
        float* o = out + ((size_t)b * KTOP + threadIdx.x) * 2;
        o[0] = rf;
        o[1] = cf;
    }
}

extern "C" void kernel_launch(void* const* d_in, const int* in_sizes, int n_in,
                              void* d_out, int out_size, void* d_ws, size_t ws_size,
                              hipStream_t stream) {
    const float* x = (const float*)d_in[0];
    float* out = (float*)d_out;
    char* ws = (char*)d_ws;

    // ws layout (bytes):
    //   [0, 1MB)       gmax   u32[16*16384]
    //   [1MB, 2MB)     glist  u32[16*16384]
    //   @2MB           gcount u32[16]
    //   @2MB+64        cutb   u32[16]
    //   @2MB+128       cnt    u32[16]
    //   @2MB+256       cand   u64[16*8192]  (1MB)
    u32* gmax   = (u32*)ws;
    u32* glist  = (u32*)(ws + (1u << 20));
    u32* gcount = (u32*)(ws + (2u << 20));
    u32* cutb   = (u32*)(ws + (2u << 20) + 64);
    u32* cnt    = (u32*)(ws + (2u << 20) + 128);
    u64* cand   = (u64*)(ws + (2u << 20) + 256);

    hipMemsetAsync(cnt, 0, 64, stream);
    hipLaunchKernelGGL(harris_a, dim3(64, NB), dim3(256), 0, stream, x, gmax);
    hipLaunchKernelGGL(select_b, dim3(NB), dim3(512), 0, stream, gmax, glist, gcount, cutb);
    hipLaunchKernelGGL(refine_c, dim3(32, NB), dim3(256), 0, stream, x, glist, gcount, cutb, cnt, cand);
    hipLaunchKernelGGL(sort_d, dim3(NB), dim3(1024), 0, stream, cnt, cand, out);
}

// Round 8
// 119.738 us; speedup vs baseline: 2.6360x; 1.7941x over previous
//
#include <hip/hip_runtime.h>
#include <stdint.h>

#define HH 1024
#define WW 1024
#define NB 16
#define KTOP 512
#define NBINS 4096
#define CAP 8192
#define ROWS 16          // output rows per wave-chunk

typedef unsigned long long u64;
typedef unsigned int u32;

__device__ __forceinline__ u32 fmap(float v) {
    u32 u = __float_as_uint(v);
    return (u & 0x80000000u) ? ~u : (u | 0x80000000u);
}
// contraction-proof scalar ops: guarantee bit-identical trees across kernels
__device__ __forceinline__ float fadd(float a, float b){ return __fadd_rn(a,b); }
__device__ __forceinline__ float fsub(float a, float b){ return __fsub_rn(a,b); }
__device__ __forceinline__ float fmul(float a, float b){ return __fmul_rn(a,b); }
__device__ __forceinline__ float add3(float a, float b, float c){ return fadd(fadd(a,b),c); }
// channel mean: IEEE division by 3 — matches rounds 1-5's validated tree
__device__ __forceinline__ float mean3(float a, float b, float c){
    return __fdiv_rn(add3(a,b,c), 3.0f);
}

__device__ __forceinline__ float g9(float w00,float w01,float w02,
                                    float w10,float w11,float w12,
                                    float w20,float w21,float w22){
    float s = fadd(w00, fmul(2.0f,w01));
    s = fadd(s, w02);
    s = fadd(s, fmul(2.0f,w10));
    s = fadd(s, fmul(4.0f,w11));
    s = fadd(s, fmul(2.0f,w12));
    s = fadd(s, w20);
    s = fadd(s, fmul(2.0f,w21));
    s = fadd(s, w22);
    return fmul(s, 0.0625f);
}
__device__ __forceinline__ u32 respkey(float Sxx,float Syy,float Sxy,bool masked){
    float det = fsub(fmul(Sxx,Syy), fmul(Sxy,Sxy));
    float tr  = fadd(Sxx,Syy);
    float R   = fsub(det, fmul(fmul(0.04f,tr),tr));
    if (masked) R = 0.0f;
    return fmap(R);
}

__device__ __forceinline__ float4 vmean(float4 a, float4 b, float4 c){
    return make_float4(mean3(a.x,b.x,c.x), mean3(a.y,b.y,c.y),
                       mean3(a.z,b.z,c.z), mean3(a.w,b.w,c.w));
}
__device__ __forceinline__ float4 vadd3(float4 a, float4 b, float4 c){
    return make_float4(add3(a.x,b.x,c.x), add3(a.y,b.y,c.y),
                       add3(a.z,b.z,c.z), add3(a.w,b.w,c.w));
}
__device__ __forceinline__ float4 vsub(float4 a, float4 b){
    return make_float4(fsub(a.x,b.x), fsub(a.y,b.y), fsub(a.z,b.z), fsub(a.w,b.w));
}
__device__ __forceinline__ float4 vmul(float4 a, float4 b){
    return make_float4(fmul(a.x,b.x), fmul(a.y,b.y), fmul(a.z,b.z), fmul(a.w,b.w));
}
// value at col-1 per slot (shift right in memory order); edge fixes lane 0
__device__ __forceinline__ float4 shl1(float4 v, float edge, int lane){
    float w = __shfl_up(v.w, 1);
    if (lane == 0) w = edge;
    return make_float4(w, v.x, v.y, v.z);
}
// value at col+1 per slot; edge fixes lane 63
__device__ __forceinline__ float4 shr1(float4 v, float edge, int lane){
    float e = __shfl_down(v.x, 1);
    if (lane == 63) e = edge;
    return make_float4(v.y, v.z, v.w, e);
}

// ---------------------------------------------------------------------------
// Pass A: register-streaming Harris. One wave = 256-px strip x 16 output rows.
// No LDS, no barriers. Writes per-(row,64px) granule max key only.
__global__ __launch_bounds__(256) void harris_a(const float* __restrict__ x,
                                                u32* __restrict__ gmax) {
    const int b     = blockIdx.y;
    const int task  = blockIdx.x * 4 + (threadIdx.x >> 6);
    const int lane  = threadIdx.x & 63;
    const int strip = task & 3;
    const int y0    = (task >> 2) * ROWS;
    const int sx    = strip * 256;
    const int cx    = sx + 4 * lane;
    const int hx    = (lane < 32) ? max(sx - 4, 0) : min(sx + 256, WW - 4);
    const float* p0 = x + (size_t)b * 3 * HH * WW;
    const float* p1 = p0 + HH * WW;
    const float* p2 = p1 + HH * WW;

    float4 z4 = make_float4(0.f,0.f,0.f,0.f);
    float4 m0=z4,m1=z4,m2=z4, mh0=z4,mh1=z4,mh2=z4, h0=z4,h1=z4,h2=z4;
    float he0=0.f,he1=0.f,he2=0.f;
    float4 xx0=z4,xx1=z4,xx2=z4, yy0=z4,yy1=z4,yy2=z4, xy0=z4,xy1=z4,xy2=z4;
    float exx0=0.f,exx1=0.f,exx2=0.f, eyy0=0.f,eyy1=0.f,eyy2=0.f, exy0=0.f,exy1=0.f,exy2=0.f;

    #pragma unroll
    for (int t = 0; t < ROWS + 4; ++t) {
        // roll mean/h state
        m0=m1; m1=m2; mh0=mh1; mh1=mh2; h0=h1; h1=h2; he0=he1; he1=he2;
        int ym = min(max(y0 - 2 + t, 0), HH - 1);
        size_t ro = (size_t)ym * WW;
        float4 a0 = *(const float4*)(p0 + ro + cx);
        float4 a1 = *(const float4*)(p1 + ro + cx);
        float4 a2 = *(const float4*)(p2 + ro + cx);
        m2 = vmean(a0, a1, a2);
        float4 b0 = *(const float4*)(p0 + ro + hx);
        float4 b1 = *(const float4*)(p1 + ro + hx);
        float4 b2 = *(const float4*)(p2 + ro + hx);
        mh2 = vmean(b0, b1, b2);
        // horizontal sums of this mean row
        float4 m2l = shl1(m2, mh2.w, lane);
        float4 m2r = shr1(m2, mh2.x, lane);
        h2  = vadd3(m2l, m2, m2r);
        he2 = (lane < 32) ? add3(mh2.z, mh2.w, m2.x) : add3(m2.w, mh2.x, mh2.y);

        if (t >= 2) {
            // products row p = ym-1 (mean rows m0,m1,m2 = p-1,p,p+1)
            xx0=xx1; xx1=xx2; yy0=yy1; yy1=yy2; xy0=xy1; xy1=xy2;
            exx0=exx1; exx1=exx2; eyy0=eyy1; eyy1=eyy2; exy0=exy1; exy1=exy2;
            float4 s  = vadd3(m0, m1, m2);
            float4 sh = vadd3(mh0, mh1, mh2);
            float4 sl = shl1(s, sh.w, lane);
            float4 sr = shr1(s, sh.x, lane);
            float4 dx = vsub(sr, sl);
            float4 dy = vsub(h2, h0);
            xx2 = vmul(dx, dx); yy2 = vmul(dy, dy); xy2 = vmul(dx, dy);
            float dxe = (lane < 32) ? fsub(s.x, sh.z) : fsub(sh.y, s.w);
            float dye = fsub(he2, he0);
            exx2 = fmul(dxe, dxe); eyy2 = fmul(dye, dye); exy2 = fmul(dxe, dye);
        }
        if (t >= 4) {
            int y = y0 + t - 4;
            bool rowm = (y < 5) || (y > HH - 6);
            float4 xxl0 = shl1(xx0, exx0, lane), xxr0 = shr1(xx0, exx0, lane);
            float4 xxl1 = shl1(xx1, exx1, lane), xxr1 = shr1(xx1, exx1, lane);
            float4 xxl2 = shl1(xx2, exx2, lane), xxr2 = shr1(xx2, exx2, lane);
            float4 yyl0 = shl1(yy0, eyy0, lane), yyr0 = shr1(yy0, eyy0, lane);
            float4 yyl1 = shl1(yy1, eyy1, lane), yyr1 = shr1(yy1, eyy1, lane);
            float4 yyl2 = shl1(yy2, eyy2, lane), yyr2 = shr1(yy2, eyy2, lane);
            float4 xyl0 = shl1(xy0, exy0, lane), xyr0 = shr1(xy0, exy0, lane);
            float4 xyl1 = shl1(xy1, exy1, lane), xyr1 = shr1(xy1, exy1, lane);
            float4 xyl2 = shl1(xy2, exy2, lane), xyr2 = shr1(xy2, exy2, lane);

            u32 k[4];
            {
                float Sxx, Syy, Sxy; int gx; bool mk;
                Sxx = g9(xxl0.x,xx0.x,xxr0.x, xxl1.x,xx1.x,xxr1.x, xxl2.x,xx2.x,xxr2.x);
                Syy = g9(yyl0.x,yy0.x,yyr0.x, yyl1.x,yy1.x,yyr1.x, yyl2.x,yy2.x,yyr2.x);
                Sxy = g9(xyl0.x,xy0.x,xyr0.x, xyl1.x,xy1.x,xyr1.x, xyl2.x,xy2.x,xyr2.x);
                gx = cx + 0; mk = rowm || (gx < 5) || (gx > WW - 6);
                k[0] = respkey(Sxx, Syy, Sxy, mk);
                Sxx = g9(xxl0.y,xx0.y,xxr0.y, xxl1.y,xx1.y,xxr1.y, xxl2.y,xx2.y,xxr2.y);
                Syy = g9(yyl0.y,yy0.y,yyr0.y, yyl1.y,yy1.y,yyr1.y, yyl2.y,yy2.y,yyr2.y);
                Sxy = g9(xyl0.y,xy0.y,xyr0.y, xyl1.y,xy1.y,xyr1.y, xyl2.y,xy2.y,xyr2.y);
                gx = cx + 1; mk = rowm || (gx < 5) || (gx > WW - 6);
                k[1] = respkey(Sxx, Syy, Sxy, mk);
                Sxx = g9(xxl0.z,xx0.z,xxr0.z, xxl1.z,xx1.z,xxr1.z, xxl2.z,xx2.z,xxr2.z);
                Syy = g9(yyl0.z,yy0.z,yyr0.z, yyl1.z,yy1.z,yyr1.z, yyl2.z,yy2.z,yyr2.z);
                Sxy = g9(xyl0.z,xy0.z,xyr0.z, xyl1.z,xy1.z,xyr1.z, xyl2.z,xy2.z,xyr2.z);
                gx = cx + 2; mk = rowm || (gx < 5) || (gx > WW - 6);
                k[2] = respkey(Sxx, Syy, Sxy, mk);
                Sxx = g9(xxl0.w,xx0.w,xxr0.w, xxl1.w,xx1.w,xxr1.w, xxl2.w,xx2.w,xxr2.w);
                Syy = g9(yyl0.w,yy0.w,yyr0.w, yyl1.w,yy1.w,yyr1.w, yyl2.w,yy2.w,yyr2.w);
                Sxy = g9(xyl0.w,xy0.w,xyr0.w, xyl1.w,xy1.w,xyr1.w, xyl2.w,xy2.w,xyr2.w);
                gx = cx + 3; mk = rowm || (gx < 5) || (gx > WW - 6);
                k[3] = respkey(Sxx, Syy, Sxy, mk);
            }
            u32 km = max(max(k[0], k[1]), max(k[2], k[3]));
            #pragma unroll
            for (int off = 1; off < 16; off <<= 1)
                km = max(km, (u32)__shfl_xor((int)km, off));
            if ((lane & 15) == 0)
                gmax[((size_t)b << 14) | ((size_t)y << 4) | (u32)(strip * 4 + (lane >> 4))] = km;
        }
    }
}

// ---------------------------------------------------------------------------
// Pass B (per batch): bin 16K granule maxes, pick largest bin with
// granule-suffix >= KTOP (sound cutoff), compact qualifying granule ids.
__global__ __launch_bounds__(512) void select_b(const u32* __restrict__ gmax,
                                                u32* __restrict__ glist,
                                                u32* __restrict__ gcount,
                                                u32* __restrict__ cutb) {
    __shared__ u32 hist[NBINS];
    __shared__ u32 wsum[8];
    __shared__ u32 s_cut, s_n;
    const int b = blockIdx.x;
    const int tid = threadIdx.x;
    const u32* gm = gmax + ((size_t)b << 14);
    u32 val[32];
    #pragma unroll
    for (int j = 0; j < 8; ++j) {
        uint4 v = ((const uint4*)gm)[tid + j * 512];
        val[j*4+0]=v.x; val[j*4+1]=v.y; val[j*4+2]=v.z; val[j*4+3]=v.w;
    }
    for (int i = tid; i < NBINS; i += 512) hist[i] = 0u;
    if (tid == 0) s_n = 0u;
    __syncthreads();
    #pragma unroll
    for (int j = 0; j < 32; ++j) atomicAdd(&hist[val[j] >> 20], 1u);
    __syncthreads();
    u32 lv[8], ls = 0;
    #pragma unroll
    for (int i = 0; i < 8; ++i) { lv[i] = hist[tid*8+i]; ls += lv[i]; }
    const int lane = tid & 63, w = tid >> 6;
    u32 v = ls;
    #pragma unroll
    for (int off = 1; off < 64; off <<= 1) {
        u32 t2 = (u32)__shfl_down((int)v, off);
        if (lane + off < 64) v += t2;
    }
    if (lane == 0) wsum[w] = v;
    __syncthreads();
    u32 excl = v - ls;
    #pragma unroll
    for (int i = 0; i < 8; ++i) if (i > w) excl += wsum[i];
    if (excl < KTOP && excl + ls >= KTOP) {       // exactly one thread
        u32 acc = excl;
        #pragma unroll
        for (int i = 7; i >= 0; --i) {
            acc += lv[i];
            if (acc >= KTOP) { s_cut = (u32)(tid*8 + i); break; }
        }
    }
    __syncthreads();
    const u32 cut = s_cut;
    u32* gl = glist + ((size_t)b << 14);
    #pragma unroll
    for (int j = 0; j < 8; ++j)
        #pragma unroll
        for (int kk = 0; kk < 4; ++kk) {
            u32 gv = val[j*4+kk];
            if ((gv >> 20) >= cut) {
                u32 q = atomicAdd(&s_n, 1u);
                gl[q] = (u32)(j*2048 + 4*tid + kk);
            }
        }
    __syncthreads();
    if (tid == 0) { gcount[b] = s_n; cutb[b] = cut; }
}

// ---------------------------------------------------------------------------
// Exact per-pixel recompute: identical _rn expression trees as harris_a.
__device__ __forceinline__ u32 harris_px(const float* __restrict__ p0,
                                         const float* __restrict__ p1,
                                         const float* __restrict__ p2,
                                         int gy, int gx) {
    if (gy < 5 || gy > HH - 6 || gx < 5 || gx > WW - 6) return 0x80000000u;
    float m[5][5];
    #pragma unroll
    for (int r = 0; r < 5; ++r)
        #pragma unroll
        for (int c = 0; c < 5; ++c) {
            size_t o = (size_t)(gy - 2 + r) * WW + (gx - 2 + c);
            m[r][c] = mean3(p0[o], p1[o], p2[o]);
        }
    float pxx[3][3], pyy[3][3], pxy[3][3];
    #pragma unroll
    for (int pr = 0; pr < 3; ++pr) {
        float s[5], ht[3], hb[3];
        #pragma unroll
        for (int c = 0; c < 5; ++c) s[c] = add3(m[pr][c], m[pr+1][c], m[pr+2][c]);
        #pragma unroll
        for (int c = 0; c < 3; ++c) {
            ht[c] = add3(m[pr][c],   m[pr][c+1],   m[pr][c+2]);
            hb[c] = add3(m[pr+2][c], m[pr+2][c+1], m[pr+2][c+2]);
        }
        #pragma unroll
        for (int pc = 0; pc < 3; ++pc) {
            float dx = fsub(s[pc+2], s[pc]);
            float dy = fsub(hb[pc], ht[pc]);
            pxx[pr][pc] = fmul(dx, dx);
            pyy[pr][pc] = fmul(dy, dy);
            pxy[pr][pc] = fmul(dx, dy);
        }
    }
    float Sxx = g9(pxx[0][0],pxx[0][1],pxx[0][2],pxx[1][0],pxx[1][1],pxx[1][2],pxx[2][0],pxx[2][1],pxx[2][2]);
    float Syy = g9(pyy[0][0],pyy[0][1],pyy[0][2],pyy[1][0],pyy[1][1],pyy[1][2],pyy[2][0],pyy[2][1],pyy[2][2]);
    float Sxy = g9(pxy[0][0],pxy[0][1],pxy[0][2],pxy[1][0],pxy[1][1],pxy[1][2],pxy[2][0],pxy[2][1],pxy[2][2]);
    return respkey(Sxx, Syy, Sxy, false);
}

// Pass C: recompute surviving granules; hits staged in block LDS (LDS atomics),
// ONE global atomicAdd per block on a per-batch padded counter (no same-line storm).
__global__ __launch_bounds__(256) void refine_c(const float* __restrict__ x,
                                                const u32* __restrict__ glist,
                                                const u32* __restrict__ gcount,
                                                const u32* __restrict__ cutb,
                                                u32* __restrict__ cnt,
                                                u64* __restrict__ cand) {
    __shared__ u64 sbuf[CAP];       // 64 KB staging
    __shared__ u32 s_n, s_base;
    const int b = blockIdx.y;
    const u32 gc  = gcount[b];
    const u32 cut = cutb[b];
    const int tid = threadIdx.x;
    const int wv = tid >> 6, lane = tid & 63;
    if (tid == 0) s_n = 0u;
    __syncthreads();

    const u32 per = (gc + 31) >> 5;              // 32 blocks in x, contiguous chunks
    const u32 i0  = blockIdx.x * per;
    const u32 i1  = min(i0 + per, gc);
    const float* p0 = x + (size_t)b * 3 * HH * WW;
    const float* p1 = p0 + HH * WW;
    const float* p2 = p1 + HH * WW;
    const u32* gl = glist + ((size_t)b << 14);

    for (u32 i = i0 + wv; i < i1; i += 4) {
        u32 gid = gl[i];
        int gy = (int)(gid >> 4);
        int gx = (int)((gid & 15u) << 6) + lane;
        u32 key = harris_px(p0, p1, p2, gy, gx);
        bool pred = (key >> 20) >= cut;
        u64 mball = __ballot(pred);
        if (mball) {
            int first = __ffsll((unsigned long long)mball) - 1;
            u32 base = 0;
            if (lane == first) base = atomicAdd(&s_n, (u32)__popcll(mball));
            base = __shfl(base, first);
            if (pred) {
                u32 q = base + (u32)__popcll(mball & ((1ull << lane) - 1));
                if (q < CAP) sbuf[q] = ((u64)key << 32) | (u32)~((u32)(gy << 10) | (u32)gx);
            }
        }
    }
    __syncthreads();
    u32 n = min(s_n, (u32)CAP);
    if (tid == 0) s_base = atomicAdd(&cnt[b * 16], n);   // padded: 1 counter / 64B line
    __syncthreads();
    u32 gb = s_base;
    u64* cb = cand + (size_t)b * CAP;
    for (u32 j = tid; j < n; j += 256) {
        u32 q = gb + j;
        if (q < CAP) cb[q] = sbuf[j];
    }
}

// ---------------------------------------------------------------------------
// Pass D: per-batch bitonic sort + coords.
__global__ __launch_bounds__(1024) void sort_d(const u32* __restrict__ cnt,
                                               const u64* __restrict__ cand,
                                               float* __restrict__ out) {
    __shared__ u64 s[CAP];
    const int b = blockIdx.x;
    u32 n = cnt[b * 16];
    if (n > CAP) n = CAP;
    u32 P = 512;
    while (P < n) P <<= 1;
    for (u32 i = threadIdx.x; i < P; i += 1024)
        s[i] = (i < n) ? cand[(size_t)b * CAP + i] : 0ULL;
    __syncthreads();
    for (u32 size = 2; size <= P; size <<= 1) {
        for (u32 stride = size >> 1; stride > 0; stride >>= 1) {
            for (u32 t = threadIdx.x; t < (P >> 1); t += 1024) {
                u32 i = 2 * t - (t & (stride - 1));
                u32 j = i + stride;
                u64 a = s[i], c = s[j];
                bool desc = ((i & size) == 0);
                if (desc ? (a < c) : (a > c)) { s[i] = c; s[j] = a; }
            }
            __syncthreads();
        }
    }
    if (threadIdx.x < KTOP) {
        u64 k = s[threadIdx.x];
        u32 idx = ~(u32)k;
        u32 row = idx >> 10, col = idx & 1023;
        float rf = ((float)row * (1.0f / 1024.0f) - 0.5f) * 2.0f;
        float cf = ((float)col * (1.0f / 1024.0f) - 0.5f) * 2.0f;
        rf = fminf(fmaxf(rf, -1.0f), 1.0f);
        cf = fminf(fmaxf(cf, -1.0f), 1.0f);
        float* o = out + ((size_t)b * KTOP + threadIdx.x) * 2;
        o[0] = rf;
        o[1] = cf;
    }
}

extern "C" void kernel_launch(void* const* d_in, const int* in_sizes, int n_in,
                              void* d_out, int out_size, void* d_ws, size_t ws_size,
                              hipStream_t stream) {
    const float* x = (const float*)d_in[0];
    float* out = (float*)d_out;
    char* ws = (char*)d_ws;

    // ws layout (bytes):
    //   [0, 1MB)       gmax   u32[16*16384]
    //   [1MB, 2MB)     glist  u32[16*16384]
    //   @2MB           gcount u32[16]
    //   @2MB+64        cutb   u32[16]
    //   @2MB+128       cnt    u32[16*16]   (padded: one counter per 64B line)
    //   @2MB+2048      cand   u64[16*8192] (1MB)
    u32* gmax   = (u32*)ws;
    u32* glist  = (u32*)(ws + (1u << 20));
    u32* gcount = (u32*)(ws + (2u << 20));
    u32* cutb   = (u32*)(ws + (2u << 20) + 64);
    u32* cnt    = (u32*)(ws + (2u << 20) + 128);
    u64* cand   = (u64*)(ws + (2u << 20) + 2048);

    hipMemsetAsync(cnt, 0, 1024, stream);
    hipLaunchKernelGGL(harris_a, dim3(64, NB), dim3(256), 0, stream, x, gmax);
    hipLaunchKernelGGL(select_b, dim3(NB), dim3(512), 0, stream, gmax, glist, gcount, cutb);
    hipLaunchKernelGGL(refine_c, dim3(32, NB), dim3(256), 0, stream, x, glist, gcount, cutb, cnt, cand);
    hipLaunchKernelGGL(sort_d, dim3(NB), dim3(1024), 0, stream, cnt, cand, out);
}